// Round 9
// baseline (228.066 us; speedup 1.0000x reference)
//
#include <hip/hip_runtime.h>

// Problem constants
constexpr int kB  = 16;    // batch
constexpr int kC  = 16;    // CI == CO
constexpr int kM  = 6;     // M1 == M2 == M3
constexpr int kNT = 39;
constexpr int kNX = 14;    // NXr
constexpr int kNY = 14;    // NYr
constexpr int kNS = kNX * kNY;       // 196
constexpr int kNF = kNT * kNS;       // 7644
constexpr int kNIK = kC * kC;        // 256
constexpr int kMR = kM * kM * kM;    // 216
constexpr int kFCH = 6;              // f-chunk for k_or1 (7644 = 6*1274)
constexpr int kVS = 256;             // padded s-stride for V

__device__ __forceinline__ float2 cmul(float2 a, float2 b) {
    return make_float2(a.x * b.x - a.y * b.y, a.x * b.y + a.y * b.x);
}
__device__ __forceinline__ void cfma(float2& c, float2 a, float2 b) {
    c.x = fmaf(a.x, b.x, fmaf(-a.y, b.y, c.x));
    c.y = fmaf(a.x, b.y, fmaf(a.y, b.x, c.y));
}

// ---------------------------------------------------------------------------
// K0: DFT matrices + pole-reciprocal tables r1/r2/r3 + exp tables e1/e2/e3
// ---------------------------------------------------------------------------
__global__ __launch_bounds__(256) void k_init(
    const float* __restrict__ wp1_re, const float* __restrict__ wp1_im,
    const float* __restrict__ wp2_re, const float* __restrict__ wp2_im,
    const float* __restrict__ wp3_re, const float* __restrict__ wp3_im,
    float2* __restrict__ F39, float2* __restrict__ F14,
    float2* __restrict__ r1t, float2* __restrict__ r2t, float2* __restrict__ r3t,
    float2* __restrict__ e1t, float2* __restrict__ e2t, float2* __restrict__ e3t)
{
    const float PI2 = 6.283185307179586f;
    int tid = blockIdx.x * blockDim.x + threadIdx.x;
    int nth = gridDim.x * blockDim.x;

    for (int idx = tid; idx < kNT * kNT; idx += nth) {
        int m = idx / kNT, t = idx % kNT;
        float ang = -PI2 * (float)((m * t) % kNT) / (float)kNT;
        float s, c; sincosf(ang, &s, &c);
        F39[idx] = make_float2(c, s);
    }
    for (int idx = tid; idx < kNX * kNX; idx += nth) {
        int a = idx / kNX, b = idx % kNX;
        float ang = -PI2 * (float)((a * b) % kNX) / (float)kNX;
        float s, c; sincosf(ang, &s, &c);
        F14[idx] = make_float2(c, s);
    }
    for (int idx = tid; idx < kNIK * kM * kNT; idx += nth) {
        int z = idx % kNT; int ikp = idx / kNT;
        float wre = wp1_re[ikp], wim = wp1_im[ikp];
        float f = (z < 20 ? (float)z : (float)(z - kNT)) / (float)kNT;
        float w = PI2 * f;
        float dr = -wre, di = w - wim;
        float inv = 1.0f / (dr * dr + di * di);
        r1t[idx] = make_float2(dr * inv, -di * inv);
        float tt = (float)z;
        float er = expf(wre * tt);
        float s, c; sincosf(wim * tt, &s, &c);
        e1t[idx] = make_float2(er * c, er * s);
    }
    for (int idx = tid; idx < kNIK * kM * kNX; idx += nth) {
        int n = idx % kNX; int ikq = idx / kNX;
        float f = (n <= 6 ? (float)n : (float)(n - kNX)) * 27.0f / 14.0f;
        float w = PI2 * f;
        float tx = (float)n * (1.0f / 27.0f);
        {
            float wre = wp2_re[ikq], wim = wp2_im[ikq];
            float dr = -wre, di = w - wim;
            float inv = 1.0f / (dr * dr + di * di);
            r2t[idx] = make_float2(dr * inv, -di * inv);
            float er = expf(wre * tx);
            float s, c; sincosf(wim * tx, &s, &c);
            e2t[idx] = make_float2(er * c, er * s);
        }
        {
            float wre = wp3_re[ikq], wim = wp3_im[ikq];
            float dr = -wre, di = w - wim;
            float inv = 1.0f / (dr * dr + di * di);
            r3t[idx] = make_float2(dr * inv, -di * inv);
            float er = expf(wre * tx);
            float s, c; sincosf(wim * tx, &s, &c);
            e3t[idx] = make_float2(er * c, er * s);
        }
    }
}

// ---------------------------------------------------------------------------
// Forward t-DFT of real x, register-column form. grid (bc, 3); thread owns s.
// ---------------------------------------------------------------------------
__global__ __launch_bounds__(256) void k_dft_t_real(
    const float* __restrict__ x, const float2* __restrict__ F39, float2* __restrict__ out)
{
    int bc = blockIdx.x, mg = blockIdx.y;
    __shared__ float2 Fs[13 * kNT];
    int t = threadIdx.x;
    for (int j = t; j < 13 * kNT; j += 256)
        Fs[j] = F39[(mg * 13 + j / kNT) * kNT + (j % kNT)];
    __syncthreads();
    if (t < kNS) {
        float col[kNT];
        const float* xp = x + (size_t)bc * kNF + t;
        #pragma unroll
        for (int tt = 0; tt < kNT; ++tt) col[tt] = xp[(size_t)tt * kNS];
        for (int mi = 0; mi < 13; ++mi) {
            float2 acc = make_float2(0.f, 0.f);
            #pragma unroll
            for (int tt = 0; tt < kNT; ++tt) {
                float2 f = Fs[mi * kNT + tt];
                acc.x = fmaf(f.x, col[tt], acc.x);
                acc.y = fmaf(f.y, col[tt], acc.y);
            }
            out[((size_t)bc * kNT + mg * 13 + mi) * kNS + t] = acc;
        }
    }
}

// ---------------------------------------------------------------------------
// Inverse t-DFT (conj F), register-column form. grid (bk, 3); thread owns s.
// ---------------------------------------------------------------------------
__global__ __launch_bounds__(256) void k_idft_t(
    const float2* __restrict__ in, const float2* __restrict__ F39, float2* __restrict__ out)
{
    int bk = blockIdx.x, zg = blockIdx.y;
    __shared__ float2 Fs[13 * kNT];
    int t = threadIdx.x;
    for (int j = t; j < 13 * kNT; j += 256) {
        float2 f = F39[(zg * 13 + j / kNT) * kNT + (j % kNT)];
        f.y = -f.y;
        Fs[j] = f;
    }
    __syncthreads();
    if (t < kNS) {
        float2 col[kNT];
        const float2* ip = in + (size_t)bk * kNF + t;
        #pragma unroll
        for (int m = 0; m < kNT; ++m) col[m] = ip[(size_t)m * kNS];
        for (int zi = 0; zi < 13; ++zi) {
            float2 acc = make_float2(0.f, 0.f);
            #pragma unroll
            for (int m = 0; m < kNT; ++m) cfma(acc, Fs[zi * kNT + m], col[m]);
            out[((size_t)bk * kNT + zg * 13 + zi) * kNS + t] = acc;
        }
    }
}

// ---------------------------------------------------------------------------
// Fused forward x+y DFT on one 14x14 tile. Block per (bc*39+m).
// ---------------------------------------------------------------------------
__global__ __launch_bounds__(256) void k_dft_xy(
    const float2* __restrict__ in, const float2* __restrict__ F14, float2* __restrict__ out)
{
    int bm = blockIdx.x;
    __shared__ float2 tile[kNS];
    __shared__ float2 tmp[kNS];
    __shared__ float2 Fs[kNX * kNX];
    int t = threadIdx.x;
    if (t < kNS) tile[t] = in[(size_t)bm * kNS + t];
    if (t < kNX * kNX) Fs[t] = F14[t];
    __syncthreads();
    if (t < kNS) {
        int n2 = t / kNY, l = t % kNY;
        float2 acc = make_float2(0.f, 0.f);
        #pragma unroll
        for (int n = 0; n < kNX; ++n) cfma(acc, Fs[n2 * kNX + n], tile[n * kNY + l]);
        tmp[t] = acc;
    }
    __syncthreads();
    if (t < kNS) {
        int n = t / kNY, l2 = t % kNY;
        float2 acc = make_float2(0.f, 0.f);
        #pragma unroll
        for (int l = 0; l < kNY; ++l) cfma(acc, Fs[l2 * kNY + l], tmp[n * kNY + l]);
        out[(size_t)bm * kNS + t] = acc;
    }
}

// Fused inverse x+y DFT + take-real + scale + add into output.
__global__ __launch_bounds__(256) void k_idft_xy_final(
    const float2* __restrict__ in, const float2* __restrict__ F14, float* __restrict__ outp)
{
    int bm = blockIdx.x;
    __shared__ float2 tile[kNS];
    __shared__ float2 tmp[kNS];
    __shared__ float2 Fs[kNX * kNX];
    int t = threadIdx.x;
    if (t < kNS) tile[t] = in[(size_t)bm * kNS + t];
    if (t < kNX * kNX) { float2 f = F14[t]; f.y = -f.y; Fs[t] = f; }
    __syncthreads();
    if (t < kNS) {
        int n2 = t / kNY, l = t % kNY;
        float2 acc = make_float2(0.f, 0.f);
        #pragma unroll
        for (int n = 0; n < kNX; ++n) cfma(acc, Fs[n2 * kNX + n], tile[n * kNY + l]);
        tmp[t] = acc;
    }
    __syncthreads();
    if (t < kNS) {
        int n = t / kNY, l2 = t % kNY;
        float2 acc = make_float2(0.f, 0.f);
        #pragma unroll
        for (int l = 0; l < kNY; ++l) cfma(acc, Fs[l2 * kNY + l], tmp[n * kNY + l]);
        outp[(size_t)bm * kNS + t] += acc.x * (1.0f / 7644.0f);
    }
}

// ---------------------------------------------------------------------------
// K4: H[i,k,m,n,l] = sum_{p,q,r} wr[i,k,p,q,r] r1[m] r2[n] r3[l]; block per (i,k)
// ---------------------------------------------------------------------------
__global__ __launch_bounds__(256) void k_H(
    const float* __restrict__ wr_re, const float* __restrict__ wr_im,
    const float2* __restrict__ r1t, const float2* __restrict__ r2t,
    const float2* __restrict__ r3t, float2* __restrict__ H)
{
    int ik = blockIdx.x;
    __shared__ float2 wrs[kMR];
    __shared__ float2 r1s[kM * kNT];
    __shared__ float2 r2s[kM * kNX];
    __shared__ float2 r3s[kM * kNY];
    __shared__ float2 As[kM * kM * kNY];
    __shared__ float2 Ss[kM * kNS];
    int t = threadIdx.x;
    for (int j = t; j < kMR; j += 256)
        wrs[j] = make_float2(wr_re[ik * kMR + j], wr_im[ik * kMR + j]);
    for (int j = t; j < kM * kNT; j += 256) r1s[j] = r1t[(size_t)ik * kM * kNT + j];
    for (int j = t; j < kM * kNX; j += 256) r2s[j] = r2t[(size_t)ik * kM * kNX + j];
    for (int j = t; j < kM * kNY; j += 256) r3s[j] = r3t[(size_t)ik * kM * kNY + j];
    __syncthreads();
    for (int j = t; j < kM * kM * kNY; j += 256) {
        int l = j % kNY; int pq = j / kNY;
        float2 acc = make_float2(0.f, 0.f);
        #pragma unroll
        for (int r = 0; r < kM; ++r) cfma(acc, wrs[pq * kM + r], r3s[r * kNY + l]);
        As[j] = acc;
    }
    __syncthreads();
    for (int j = t; j < kM * kNS; j += 256) {
        int l = j % kNY; int n = (j / kNY) % kNX; int p = j / kNS;
        float2 acc = make_float2(0.f, 0.f);
        #pragma unroll
        for (int q = 0; q < kM; ++q) cfma(acc, r2s[q * kNX + n], As[(p * kM + q) * kNY + l]);
        Ss[j] = acc;
    }
    __syncthreads();
    for (int j = t; j < kNF; j += 256) {
        int m = j / kNS; int nl = j % kNS;
        float2 acc = make_float2(0.f, 0.f);
        #pragma unroll
        for (int p = 0; p < kM; ++p) cfma(acc, r1s[p * kNT + m], Ss[p * kNS + nl]);
        H[(size_t)ik * kNF + j] = acc;
    }
}

// ---------------------------------------------------------------------------
// K5: or1[b,k,f] = sum_i alpha[b,i,f] * H[i,k,f]
// f-chunked, LDS-staged (16x reuse). One block per 6 f's; thread = (b,k).
// ---------------------------------------------------------------------------
__global__ __launch_bounds__(256) void k_or1(
    const float2* __restrict__ alpha, const float2* __restrict__ H, float2* __restrict__ out)
{
    int f0 = blockIdx.x * kFCH;
    __shared__ float2 As[256 * 7 + 16];
    __shared__ float2 Hs[256 * 7 + 16];
    int t = threadIdx.x;
    {
        const float2* ap = alpha + (size_t)t * kNF + f0;
        const float2* hp = H + (size_t)t * kNF + f0;
        int base = t * 7 + (t >> 4);
        #pragma unroll
        for (int j = 0; j < kFCH; ++j) {
            As[base + j] = ap[j];
            Hs[base + j] = hp[j];
        }
    }
    __syncthreads();
    int b = t >> 4, k = t & 15;
    float2 acc[kFCH];
    #pragma unroll
    for (int j = 0; j < kFCH; ++j) acc[j] = make_float2(0.f, 0.f);
    #pragma unroll
    for (int i = 0; i < kC; ++i) {
        int ai = (b * 16 + i) * 7 + b;
        int hi = (i * 16 + k) * 7 + i;
        #pragma unroll
        for (int j = 0; j < kFCH; ++j) cfma(acc[j], As[ai + j], Hs[hi + j]);
    }
    float2* op = out + (size_t)t * kNF + f0;
    #pragma unroll
    for (int j = 0; j < kFCH; ++j) op[j] = acc[j];
}

// ---------------------------------------------------------------------------
// K7a: partial or2 per (b-pair,k,i). Tables (ik) amortized across 2 batches.
// P[((b*16+k)*16+i)*216+t] = wr[ik,t] * G[b,i,k,t]
// ---------------------------------------------------------------------------
__global__ __launch_bounds__(256) void k_or2p(
    const float2* __restrict__ alpha,
    const float* __restrict__ wr_re, const float* __restrict__ wr_im,
    const float2* __restrict__ r1t, const float2* __restrict__ r2t,
    const float2* __restrict__ r3t, float2* __restrict__ P)
{
    int blk = blockIdx.x;            // (pb*16 + k)*16 + i
    int i = blk % kC; int rest = blk / kC;
    int k = rest % kC; int pb = rest / kC;
    int b0 = 2 * pb, b1 = 2 * pb + 1;
    int ik = i * kC + k;
    __shared__ float2 r1s[kM * kNT];
    __shared__ float2 r2s[kM * kNX];
    __shared__ float2 r3s[kM * kNY];
    __shared__ float2 wrs[kMR];
    __shared__ float2 T1a[kM * kNS];
    __shared__ float2 T1b[kM * kNS];
    __shared__ float2 T2a[kM * kM * kNY];
    __shared__ float2 T2b[kM * kM * kNY];
    int t = threadIdx.x;
    for (int j = t; j < kM * kNT; j += 256) r1s[j] = r1t[(size_t)ik * kM * kNT + j];
    for (int j = t; j < kM * kNX; j += 256) r2s[j] = r2t[(size_t)ik * kM * kNX + j];
    for (int j = t; j < kM * kNY; j += 256) r3s[j] = r3t[(size_t)ik * kM * kNY + j];
    for (int j = t; j < kMR; j += 256)
        wrs[j] = make_float2(wr_re[ik * kMR + j], wr_im[ik * kMR + j]);
    __syncthreads();
    if (t < kNS) {
        float2 c0 = make_float2(0.f, 0.f), c1 = c0, c2 = c0, c3 = c0, c4 = c0, c5 = c0;
        float2 d0 = c0, d1 = c0, d2 = c0, d3 = c0, d4 = c0, d5 = c0;
        const float2* ap0 = alpha + (size_t)(b0 * kC + i) * kNF + t;
        const float2* ap1 = alpha + (size_t)(b1 * kC + i) * kNF + t;
        for (int m = 0; m < kNT; ++m) {
            float2 a0 = ap0[(size_t)m * kNS];
            float2 a1 = ap1[(size_t)m * kNS];
            float2 r;
            r = r1s[0 * kNT + m]; cfma(c0, a0, r); cfma(d0, a1, r);
            r = r1s[1 * kNT + m]; cfma(c1, a0, r); cfma(d1, a1, r);
            r = r1s[2 * kNT + m]; cfma(c2, a0, r); cfma(d2, a1, r);
            r = r1s[3 * kNT + m]; cfma(c3, a0, r); cfma(d3, a1, r);
            r = r1s[4 * kNT + m]; cfma(c4, a0, r); cfma(d4, a1, r);
            r = r1s[5 * kNT + m]; cfma(c5, a0, r); cfma(d5, a1, r);
        }
        T1a[0 * kNS + t] = c0; T1a[1 * kNS + t] = c1; T1a[2 * kNS + t] = c2;
        T1a[3 * kNS + t] = c3; T1a[4 * kNS + t] = c4; T1a[5 * kNS + t] = c5;
        T1b[0 * kNS + t] = d0; T1b[1 * kNS + t] = d1; T1b[2 * kNS + t] = d2;
        T1b[3 * kNS + t] = d3; T1b[4 * kNS + t] = d4; T1b[5 * kNS + t] = d5;
    }
    __syncthreads();
    for (int j = t; j < kM * kM * kNY; j += 256) {
        int l = j % kNY; int q = (j / kNY) % kM; int p = j / (kNY * kM);
        float2 a2 = make_float2(0.f, 0.f);
        float2 b2 = make_float2(0.f, 0.f);
        #pragma unroll
        for (int n = 0; n < kNX; ++n) {
            float2 r = r2s[q * kNX + n];
            cfma(a2, T1a[p * kNS + n * kNY + l], r);
            cfma(b2, T1b[p * kNS + n * kNY + l], r);
        }
        T2a[j] = a2;
        T2b[j] = b2;
    }
    __syncthreads();
    if (t < kMR) {
        int r = t % kM; int q = (t / kM) % kM; int p = t / (kM * kM);
        float2 t3a = make_float2(0.f, 0.f);
        float2 t3b = make_float2(0.f, 0.f);
        #pragma unroll
        for (int l = 0; l < kNY; ++l) {
            float2 rr = r3s[r * kNY + l];
            cfma(t3a, T2a[(p * kM + q) * kNY + l], rr);
            cfma(t3b, T2b[(p * kM + q) * kNY + l], rr);
        }
        float2 w = wrs[t];
        P[((size_t)(b0 * kC + k) * kC + i) * kMR + t] = cmul(w, t3a);
        P[((size_t)(b1 * kC + k) * kC + i) * kMR + t] = cmul(w, t3b);
    }
}

// K7b: or2[bk][t] = -sum_i P[(bk*16+i)*216+t]
__global__ __launch_bounds__(256) void k_or2red(
    const float2* __restrict__ P, float2* __restrict__ or2)
{
    int id = blockIdx.x * blockDim.x + threadIdx.x;
    if (id >= kB * kC * kMR) return;
    int t = id % kMR; int bk = id / kMR;
    float2 s = make_float2(0.f, 0.f);
    #pragma unroll
    for (int i = 0; i < kC; ++i) {
        float2 v = P[((size_t)bk * kC + i) * kMR + t];
        s.x += v.x; s.y += v.y;
    }
    or2[id] = make_float2(-s.x, -s.y);
}

// ---------------------------------------------------------------------------
// K8a: V[(bh,k),(c,p),s] = sum_q ( sum_m or2[b,c,pqm] e3[c,k,m,y] ) e2[c,k,q,x]
// One block per (bh,k,c); b = pb*8+bh. s padded to kVS=256, tail zeroed.
// ---------------------------------------------------------------------------
__global__ __launch_bounds__(256) void k_x2v(
    const float2* __restrict__ or2,
    const float2* __restrict__ e2t, const float2* __restrict__ e3t,
    float2* __restrict__ Vg, int pb)
{
    int bid = blockIdx.x;
    int c = bid & 15; int rest = bid >> 4;
    int k = rest & 15; int bh = rest >> 4;
    int b = pb * 8 + bh;
    int ck = c * kC + k;
    __shared__ float2 o2s[kMR];
    __shared__ float2 e2s[kM * kNX];
    __shared__ float2 e3s[kM * kNY];
    __shared__ float2 Us[kM * kM * kNY];
    int t = threadIdx.x;
    if (t < kMR) o2s[t] = or2[(size_t)(b * kC + c) * kMR + t];
    if (t < kM * kNX) e2s[t] = e2t[(size_t)ck * (kM * kNX) + t];
    if (t < kM * kNY) e3s[t] = e3t[(size_t)ck * (kM * kNY) + t];
    __syncthreads();
    for (int j = t; j < kM * kM * kNY; j += 256) {
        int y = j % kNY, pq = j / kNY;
        float2 u = make_float2(0.f, 0.f);
        #pragma unroll
        for (int m = 0; m < kM; ++m) cfma(u, o2s[pq * kM + m], e3s[m * kNY + y]);
        Us[j] = u;
    }
    __syncthreads();
    size_t vbase = ((size_t)(bh * kC + k) * (kC * kM) + c * kM) * kVS;
    for (int j = t; j < kM * kVS; j += 256) {
        int p = j >> 8, s = j & 255;
        float2 v = make_float2(0.f, 0.f);
        if (s < kNS) {
            int x = s / kNY, y = s % kNY;
            #pragma unroll
            for (int q = 0; q < kM; ++q)
                cfma(v, Us[(p * kM + q) * kNY + y], e2s[q * kNX + x]);
        }
        Vg[vbase + (size_t)p * kVS + s] = v;
    }
}

// ---------------------------------------------------------------------------
// K8b: out[b,k,z,s] = (1/7644) Re( sum_{cp} e1[c,k,p,z] V[(bh,k),(c,p),s] )
// grid (128 = bh*16+k, 3 z-chunks). Thread: zt=t>>6, sl=t&63; tile 4z x 4s.
// e1 reads wave-uniform broadcast; V reads 512B-coalesced. No s-guard (pad 0).
// ---------------------------------------------------------------------------
__global__ __launch_bounds__(256) void k_x2gemm(
    const float2* __restrict__ Vg, const float2* __restrict__ e1t,
    float* __restrict__ outp, int pb)
{
    int bx = blockIdx.x;
    int k = bx & 15, bh = bx >> 4;
    int b = pb * 8 + bh;
    int z0 = blockIdx.y * 13;
    __shared__ float2 e1w[96 * 16];   // [(c,p)][zloc pad16], 12.3 KB
    int t = threadIdx.x;
    for (int j = t; j < 96 * 16; j += 256) {
        int row = j >> 4, zi = j & 15;
        int c = row / kM, p = row % kM;
        float2 e = make_float2(0.f, 0.f);
        if (zi < 13)
            e = e1t[((size_t)(c * kC + k) * kM + p) * kNT + z0 + zi];
        e1w[j] = e;
    }
    __syncthreads();

    int sl = t & 63, zt = t >> 6;
    const float2* vp = Vg + (size_t)(bh * kC + k) * (kC * kM) * kVS + sl;
    float acc[4][4];
    #pragma unroll
    for (int zi = 0; zi < 4; ++zi)
        #pragma unroll
        for (int j = 0; j < 4; ++j) acc[zi][j] = 0.f;

    for (int kk = 0; kk < kC * kM; ++kk) {
        float2 vr[4];
        #pragma unroll
        for (int j = 0; j < 4; ++j) vr[j] = vp[(size_t)kk * kVS + 64 * j];
        const int e1base = kk * 16 + zt;
        #pragma unroll
        for (int zi = 0; zi < 4; ++zi) {
            float2 e = e1w[e1base + 4 * zi];
            #pragma unroll
            for (int j = 0; j < 4; ++j)
                acc[zi][j] = fmaf(vr[j].x, e.x, fmaf(-vr[j].y, e.y, acc[zi][j]));
        }
    }

    const float sc = 1.0f / 7644.0f;
    size_t base = (size_t)(b * kC + k) * kNF;
    #pragma unroll
    for (int zi = 0; zi < 4; ++zi) {
        int zloc = zt + 4 * zi;
        if (zloc < 13) {
            size_t zb = base + (size_t)(z0 + zloc) * kNS;
            #pragma unroll
            for (int j = 0; j < 4; ++j) {
                int s = sl + 64 * j;
                if (s < kNS) outp[zb + s] = acc[zi][j] * sc;
            }
        }
    }
}

// ---------------------------------------------------------------------------
extern "C" void kernel_launch(void* const* d_in, const int* in_sizes, int n_in,
                              void* d_out, int out_size, void* d_ws, size_t ws_size,
                              hipStream_t stream) {
    (void)in_sizes; (void)n_in; (void)out_size; (void)ws_size;
    const float* x      = (const float*)d_in[0];
    const float* wp1_re = (const float*)d_in[1];
    const float* wp1_im = (const float*)d_in[2];
    const float* wp2_re = (const float*)d_in[3];
    const float* wp2_im = (const float*)d_in[4];
    const float* wp3_re = (const float*)d_in[5];
    const float* wp3_im = (const float*)d_in[6];
    const float* wr_re  = (const float*)d_in[7];
    const float* wr_im  = (const float*)d_in[8];
    float* out = (float*)d_out;

    const size_t big = (size_t)kNIK * kNF;  // 1,956,864 complex
    float2* A   = (float2*)d_ws;            // dft scratch -> or1 -> (dead) -> V region
    float2* Bb  = A + big;                  // alpha -> (dead) -> V region tail
    float2* Cc  = Bb + big;                 // H -> or2 partials -> t-ifft of or1
    float2* OR2 = Cc + big;                 // 55,296
    float2* r1t = OR2 + (size_t)kB * kC * kMR;
    float2* r2t = r1t + (size_t)kNIK * kM * kNT;
    float2* r3t = r2t + (size_t)kNIK * kM * kNX;
    float2* e1t = r3t + (size_t)kNIK * kM * kNY;
    float2* e2t = e1t + (size_t)kNIK * kM * kNT;
    float2* e3t = e2t + (size_t)kNIK * kM * kNX;
    float2* F39 = e3t + (size_t)kNIK * kM * kNY;
    float2* F14 = F39 + kNT * kNT;
    float2* Vg  = (float2*)d_ws;            // 128*96*256 = 3,145,728 complex <= 2*big

    k_init<<<64, 256, 0, stream>>>(wp1_re, wp1_im, wp2_re, wp2_im, wp3_re, wp3_im,
                                   F39, F14, r1t, r2t, r3t, e1t, e2t, e3t);
    // forward DFT: x -> A (t-pass) -> Bb (fused xy). alpha lives in Bb.
    k_dft_t_real<<<dim3(kNIK, 3), 256, 0, stream>>>(x, F39, A);
    k_dft_xy<<<kNIK * kNT, 256, 0, stream>>>(A, F14, Bb);
    // transfer function H -> Cc; or1 -> A
    k_H<<<kNIK, 256, 0, stream>>>(wr_re, wr_im, r1t, r2t, r3t, Cc);
    k_or1<<<kNF / kFCH, 256, 0, stream>>>(Bb, Cc, A);
    // or2: partials into Cc (H dead), reduce -> OR2. Last readers of alpha (Bb).
    k_or2p<<<(kB / 2) * kC * kC, 256, 0, stream>>>(Bb, wr_re, wr_im, r1t, r2t, r3t, Cc);
    k_or2red<<<(kB * kC * kMR + 255) / 256, 256, 0, stream>>>(Cc, OR2);
    // t-ifft of or1: A -> Cc (frees A; Cc partials are dead)
    k_idft_t<<<dim3(kB * kC, 3), 256, 0, stream>>>(A, F39, Cc);
    // x2 in two b-halves through the A∪Bb region (both dead now)
    for (int pb = 0; pb < 2; ++pb) {
        k_x2v<<<8 * kC * kC, 256, 0, stream>>>(OR2, e2t, e3t, Vg, pb);
        k_x2gemm<<<dim3(8 * kC, 3), 256, 0, stream>>>(Vg, e1t, out, pb);
    }
    // inverse xy DFT of or1 (in Cc) + add into out
    k_idft_xy_final<<<kNIK * kNT, 256, 0, stream>>>(Cc, F14, out);
}

// Round 10
// 201.156 us; speedup vs baseline: 1.1338x; 1.1338x over previous
//
#include <hip/hip_runtime.h>

// Problem constants
constexpr int kB  = 16;    // batch
constexpr int kC  = 16;    // CI == CO
constexpr int kM  = 6;     // M1 == M2 == M3
constexpr int kNT = 39;
constexpr int kNX = 14;    // NXr
constexpr int kNY = 14;    // NYr
constexpr int kNS = kNX * kNY;       // 196
constexpr int kNF = kNT * kNS;       // 7644
constexpr int kNIK = kC * kC;        // 256
constexpr int kMR = kM * kM * kM;    // 216
constexpr int kFCH = 6;              // f-chunk for k_or1 (7644 = 6*1274)
constexpr int kVS = 256;             // padded s-stride for V

__device__ __forceinline__ float2 cmul(float2 a, float2 b) {
    return make_float2(a.x * b.x - a.y * b.y, a.x * b.y + a.y * b.x);
}
__device__ __forceinline__ void cfma(float2& c, float2 a, float2 b) {
    c.x = fmaf(a.x, b.x, fmaf(-a.y, b.y, c.x));
    c.y = fmaf(a.x, b.y, fmaf(a.y, b.x, c.y));
}

// ---------------------------------------------------------------------------
// K0: DFT matrices + pole-reciprocal tables r1/r2/r3 + exp tables e1/e2/e3
// ---------------------------------------------------------------------------
__global__ __launch_bounds__(256) void k_init(
    const float* __restrict__ wp1_re, const float* __restrict__ wp1_im,
    const float* __restrict__ wp2_re, const float* __restrict__ wp2_im,
    const float* __restrict__ wp3_re, const float* __restrict__ wp3_im,
    float2* __restrict__ F39, float2* __restrict__ F14,
    float2* __restrict__ r1t, float2* __restrict__ r2t, float2* __restrict__ r3t,
    float2* __restrict__ e1t, float2* __restrict__ e2t, float2* __restrict__ e3t)
{
    const float PI2 = 6.283185307179586f;
    int tid = blockIdx.x * blockDim.x + threadIdx.x;
    int nth = gridDim.x * blockDim.x;

    for (int idx = tid; idx < kNT * kNT; idx += nth) {
        int m = idx / kNT, t = idx % kNT;
        float ang = -PI2 * (float)((m * t) % kNT) / (float)kNT;
        float s, c; sincosf(ang, &s, &c);
        F39[idx] = make_float2(c, s);
    }
    for (int idx = tid; idx < kNX * kNX; idx += nth) {
        int a = idx / kNX, b = idx % kNX;
        float ang = -PI2 * (float)((a * b) % kNX) / (float)kNX;
        float s, c; sincosf(ang, &s, &c);
        F14[idx] = make_float2(c, s);
    }
    for (int idx = tid; idx < kNIK * kM * kNT; idx += nth) {
        int z = idx % kNT; int ikp = idx / kNT;
        float wre = wp1_re[ikp], wim = wp1_im[ikp];
        float f = (z < 20 ? (float)z : (float)(z - kNT)) / (float)kNT;
        float w = PI2 * f;
        float dr = -wre, di = w - wim;
        float inv = 1.0f / (dr * dr + di * di);
        r1t[idx] = make_float2(dr * inv, -di * inv);
        float tt = (float)z;
        float er = expf(wre * tt);
        float s, c; sincosf(wim * tt, &s, &c);
        e1t[idx] = make_float2(er * c, er * s);
    }
    for (int idx = tid; idx < kNIK * kM * kNX; idx += nth) {
        int n = idx % kNX; int ikq = idx / kNX;
        float f = (n <= 6 ? (float)n : (float)(n - kNX)) * 27.0f / 14.0f;
        float w = PI2 * f;
        float tx = (float)n * (1.0f / 27.0f);
        {
            float wre = wp2_re[ikq], wim = wp2_im[ikq];
            float dr = -wre, di = w - wim;
            float inv = 1.0f / (dr * dr + di * di);
            r2t[idx] = make_float2(dr * inv, -di * inv);
            float er = expf(wre * tx);
            float s, c; sincosf(wim * tx, &s, &c);
            e2t[idx] = make_float2(er * c, er * s);
        }
        {
            float wre = wp3_re[ikq], wim = wp3_im[ikq];
            float dr = -wre, di = w - wim;
            float inv = 1.0f / (dr * dr + di * di);
            r3t[idx] = make_float2(dr * inv, -di * inv);
            float er = expf(wre * tx);
            float s, c; sincosf(wim * tx, &s, &c);
            e3t[idx] = make_float2(er * c, er * s);
        }
    }
}

// ---------------------------------------------------------------------------
// Forward t-DFT of real x, register-column form. grid (bc, 3); thread owns s.
// ---------------------------------------------------------------------------
__global__ __launch_bounds__(256) void k_dft_t_real(
    const float* __restrict__ x, const float2* __restrict__ F39, float2* __restrict__ out)
{
    int bc = blockIdx.x, mg = blockIdx.y;
    __shared__ float2 Fs[13 * kNT];
    int t = threadIdx.x;
    for (int j = t; j < 13 * kNT; j += 256)
        Fs[j] = F39[(mg * 13 + j / kNT) * kNT + (j % kNT)];
    __syncthreads();
    if (t < kNS) {
        float col[kNT];
        const float* xp = x + (size_t)bc * kNF + t;
        #pragma unroll
        for (int tt = 0; tt < kNT; ++tt) col[tt] = xp[(size_t)tt * kNS];
        for (int mi = 0; mi < 13; ++mi) {
            float2 acc = make_float2(0.f, 0.f);
            #pragma unroll
            for (int tt = 0; tt < kNT; ++tt) {
                float2 f = Fs[mi * kNT + tt];
                acc.x = fmaf(f.x, col[tt], acc.x);
                acc.y = fmaf(f.y, col[tt], acc.y);
            }
            out[((size_t)bc * kNT + mg * 13 + mi) * kNS + t] = acc;
        }
    }
}

// ---------------------------------------------------------------------------
// Inverse t-DFT (conj F), register-column form. grid (bk, 3); thread owns s.
// ---------------------------------------------------------------------------
__global__ __launch_bounds__(256) void k_idft_t(
    const float2* __restrict__ in, const float2* __restrict__ F39, float2* __restrict__ out)
{
    int bk = blockIdx.x, zg = blockIdx.y;
    __shared__ float2 Fs[13 * kNT];
    int t = threadIdx.x;
    for (int j = t; j < 13 * kNT; j += 256) {
        float2 f = F39[(zg * 13 + j / kNT) * kNT + (j % kNT)];
        f.y = -f.y;
        Fs[j] = f;
    }
    __syncthreads();
    if (t < kNS) {
        float2 col[kNT];
        const float2* ip = in + (size_t)bk * kNF + t;
        #pragma unroll
        for (int m = 0; m < kNT; ++m) col[m] = ip[(size_t)m * kNS];
        for (int zi = 0; zi < 13; ++zi) {
            float2 acc = make_float2(0.f, 0.f);
            #pragma unroll
            for (int m = 0; m < kNT; ++m) cfma(acc, Fs[zi * kNT + m], col[m]);
            out[((size_t)bk * kNT + zg * 13 + zi) * kNS + t] = acc;
        }
    }
}

// ---------------------------------------------------------------------------
// Fused forward x+y DFT on one 14x14 tile. Block per (bc*39+m).
// ---------------------------------------------------------------------------
__global__ __launch_bounds__(256) void k_dft_xy(
    const float2* __restrict__ in, const float2* __restrict__ F14, float2* __restrict__ out)
{
    int bm = blockIdx.x;
    __shared__ float2 tile[kNS];
    __shared__ float2 tmp[kNS];
    __shared__ float2 Fs[kNX * kNX];
    int t = threadIdx.x;
    if (t < kNS) tile[t] = in[(size_t)bm * kNS + t];
    if (t < kNX * kNX) Fs[t] = F14[t];
    __syncthreads();
    if (t < kNS) {
        int n2 = t / kNY, l = t % kNY;
        float2 acc = make_float2(0.f, 0.f);
        #pragma unroll
        for (int n = 0; n < kNX; ++n) cfma(acc, Fs[n2 * kNX + n], tile[n * kNY + l]);
        tmp[t] = acc;
    }
    __syncthreads();
    if (t < kNS) {
        int n = t / kNY, l2 = t % kNY;
        float2 acc = make_float2(0.f, 0.f);
        #pragma unroll
        for (int l = 0; l < kNY; ++l) cfma(acc, Fs[l2 * kNY + l], tmp[n * kNY + l]);
        out[(size_t)bm * kNS + t] = acc;
    }
}

// Fused inverse x+y DFT + take-real + scale + add into output.
__global__ __launch_bounds__(256) void k_idft_xy_final(
    const float2* __restrict__ in, const float2* __restrict__ F14, float* __restrict__ outp)
{
    int bm = blockIdx.x;
    __shared__ float2 tile[kNS];
    __shared__ float2 tmp[kNS];
    __shared__ float2 Fs[kNX * kNX];
    int t = threadIdx.x;
    if (t < kNS) tile[t] = in[(size_t)bm * kNS + t];
    if (t < kNX * kNX) { float2 f = F14[t]; f.y = -f.y; Fs[t] = f; }
    __syncthreads();
    if (t < kNS) {
        int n2 = t / kNY, l = t % kNY;
        float2 acc = make_float2(0.f, 0.f);
        #pragma unroll
        for (int n = 0; n < kNX; ++n) cfma(acc, Fs[n2 * kNX + n], tile[n * kNY + l]);
        tmp[t] = acc;
    }
    __syncthreads();
    if (t < kNS) {
        int n = t / kNY, l2 = t % kNY;
        float2 acc = make_float2(0.f, 0.f);
        #pragma unroll
        for (int l = 0; l < kNY; ++l) cfma(acc, Fs[l2 * kNY + l], tmp[n * kNY + l]);
        outp[(size_t)bm * kNS + t] += acc.x * (1.0f / 7644.0f);
    }
}

// ---------------------------------------------------------------------------
// K4: H[i,k,m,n,l] = sum_{p,q,r} wr[i,k,p,q,r] r1[m] r2[n] r3[l]; block per (i,k)
// ---------------------------------------------------------------------------
__global__ __launch_bounds__(256) void k_H(
    const float* __restrict__ wr_re, const float* __restrict__ wr_im,
    const float2* __restrict__ r1t, const float2* __restrict__ r2t,
    const float2* __restrict__ r3t, float2* __restrict__ H)
{
    int ik = blockIdx.x;
    __shared__ float2 wrs[kMR];
    __shared__ float2 r1s[kM * kNT];
    __shared__ float2 r2s[kM * kNX];
    __shared__ float2 r3s[kM * kNY];
    __shared__ float2 As[kM * kM * kNY];
    __shared__ float2 Ss[kM * kNS];
    int t = threadIdx.x;
    for (int j = t; j < kMR; j += 256)
        wrs[j] = make_float2(wr_re[ik * kMR + j], wr_im[ik * kMR + j]);
    for (int j = t; j < kM * kNT; j += 256) r1s[j] = r1t[(size_t)ik * kM * kNT + j];
    for (int j = t; j < kM * kNX; j += 256) r2s[j] = r2t[(size_t)ik * kM * kNX + j];
    for (int j = t; j < kM * kNY; j += 256) r3s[j] = r3t[(size_t)ik * kM * kNY + j];
    __syncthreads();
    for (int j = t; j < kM * kM * kNY; j += 256) {
        int l = j % kNY; int pq = j / kNY;
        float2 acc = make_float2(0.f, 0.f);
        #pragma unroll
        for (int r = 0; r < kM; ++r) cfma(acc, wrs[pq * kM + r], r3s[r * kNY + l]);
        As[j] = acc;
    }
    __syncthreads();
    for (int j = t; j < kM * kNS; j += 256) {
        int l = j % kNY; int n = (j / kNY) % kNX; int p = j / kNS;
        float2 acc = make_float2(0.f, 0.f);
        #pragma unroll
        for (int q = 0; q < kM; ++q) cfma(acc, r2s[q * kNX + n], As[(p * kM + q) * kNY + l]);
        Ss[j] = acc;
    }
    __syncthreads();
    for (int j = t; j < kNF; j += 256) {
        int m = j / kNS; int nl = j % kNS;
        float2 acc = make_float2(0.f, 0.f);
        #pragma unroll
        for (int p = 0; p < kM; ++p) cfma(acc, r1s[p * kNT + m], Ss[p * kNS + nl]);
        H[(size_t)ik * kNF + j] = acc;
    }
}

// ---------------------------------------------------------------------------
// K5: or1[b,k,f] = sum_i alpha[b,i,f] * H[i,k,f]
// f-chunked, LDS-staged (16x reuse). One block per 6 f's; thread = (b,k).
// ---------------------------------------------------------------------------
__global__ __launch_bounds__(256) void k_or1(
    const float2* __restrict__ alpha, const float2* __restrict__ H, float2* __restrict__ out)
{
    int f0 = blockIdx.x * kFCH;
    __shared__ float2 As[256 * 7 + 16];
    __shared__ float2 Hs[256 * 7 + 16];
    int t = threadIdx.x;
    {
        const float2* ap = alpha + (size_t)t * kNF + f0;
        const float2* hp = H + (size_t)t * kNF + f0;
        int base = t * 7 + (t >> 4);
        #pragma unroll
        for (int j = 0; j < kFCH; ++j) {
            As[base + j] = ap[j];
            Hs[base + j] = hp[j];
        }
    }
    __syncthreads();
    int b = t >> 4, k = t & 15;
    float2 acc[kFCH];
    #pragma unroll
    for (int j = 0; j < kFCH; ++j) acc[j] = make_float2(0.f, 0.f);
    #pragma unroll
    for (int i = 0; i < kC; ++i) {
        int ai = (b * 16 + i) * 7 + b;
        int hi = (i * 16 + k) * 7 + i;
        #pragma unroll
        for (int j = 0; j < kFCH; ++j) cfma(acc[j], As[ai + j], Hs[hi + j]);
    }
    float2* op = out + (size_t)t * kNF + f0;
    #pragma unroll
    for (int j = 0; j < kFCH; ++j) op[j] = acc[j];
}

// ---------------------------------------------------------------------------
// K7a: partial or2 per (b-pair,k,i). Tables (ik) amortized across 2 batches.
// P[((b*16+k)*16+i)*216+t] = wr[ik,t] * G[b,i,k,t]
// ---------------------------------------------------------------------------
__global__ __launch_bounds__(256) void k_or2p(
    const float2* __restrict__ alpha,
    const float* __restrict__ wr_re, const float* __restrict__ wr_im,
    const float2* __restrict__ r1t, const float2* __restrict__ r2t,
    const float2* __restrict__ r3t, float2* __restrict__ P)
{
    int blk = blockIdx.x;            // (pb*16 + k)*16 + i
    int i = blk % kC; int rest = blk / kC;
    int k = rest % kC; int pb = rest / kC;
    int b0 = 2 * pb, b1 = 2 * pb + 1;
    int ik = i * kC + k;
    __shared__ float2 r1s[kM * kNT];
    __shared__ float2 r2s[kM * kNX];
    __shared__ float2 r3s[kM * kNY];
    __shared__ float2 wrs[kMR];
    __shared__ float2 T1a[kM * kNS];
    __shared__ float2 T1b[kM * kNS];
    __shared__ float2 T2a[kM * kM * kNY];
    __shared__ float2 T2b[kM * kM * kNY];
    int t = threadIdx.x;
    for (int j = t; j < kM * kNT; j += 256) r1s[j] = r1t[(size_t)ik * kM * kNT + j];
    for (int j = t; j < kM * kNX; j += 256) r2s[j] = r2t[(size_t)ik * kM * kNX + j];
    for (int j = t; j < kM * kNY; j += 256) r3s[j] = r3t[(size_t)ik * kM * kNY + j];
    for (int j = t; j < kMR; j += 256)
        wrs[j] = make_float2(wr_re[ik * kMR + j], wr_im[ik * kMR + j]);
    __syncthreads();
    if (t < kNS) {
        float2 c0 = make_float2(0.f, 0.f), c1 = c0, c2 = c0, c3 = c0, c4 = c0, c5 = c0;
        float2 d0 = c0, d1 = c0, d2 = c0, d3 = c0, d4 = c0, d5 = c0;
        const float2* ap0 = alpha + (size_t)(b0 * kC + i) * kNF + t;
        const float2* ap1 = alpha + (size_t)(b1 * kC + i) * kNF + t;
        for (int m = 0; m < kNT; ++m) {
            float2 a0 = ap0[(size_t)m * kNS];
            float2 a1 = ap1[(size_t)m * kNS];
            float2 r;
            r = r1s[0 * kNT + m]; cfma(c0, a0, r); cfma(d0, a1, r);
            r = r1s[1 * kNT + m]; cfma(c1, a0, r); cfma(d1, a1, r);
            r = r1s[2 * kNT + m]; cfma(c2, a0, r); cfma(d2, a1, r);
            r = r1s[3 * kNT + m]; cfma(c3, a0, r); cfma(d3, a1, r);
            r = r1s[4 * kNT + m]; cfma(c4, a0, r); cfma(d4, a1, r);
            r = r1s[5 * kNT + m]; cfma(c5, a0, r); cfma(d5, a1, r);
        }
        T1a[0 * kNS + t] = c0; T1a[1 * kNS + t] = c1; T1a[2 * kNS + t] = c2;
        T1a[3 * kNS + t] = c3; T1a[4 * kNS + t] = c4; T1a[5 * kNS + t] = c5;
        T1b[0 * kNS + t] = d0; T1b[1 * kNS + t] = d1; T1b[2 * kNS + t] = d2;
        T1b[3 * kNS + t] = d3; T1b[4 * kNS + t] = d4; T1b[5 * kNS + t] = d5;
    }
    __syncthreads();
    for (int j = t; j < kM * kM * kNY; j += 256) {
        int l = j % kNY; int q = (j / kNY) % kM; int p = j / (kNY * kM);
        float2 a2 = make_float2(0.f, 0.f);
        float2 b2 = make_float2(0.f, 0.f);
        #pragma unroll
        for (int n = 0; n < kNX; ++n) {
            float2 r = r2s[q * kNX + n];
            cfma(a2, T1a[p * kNS + n * kNY + l], r);
            cfma(b2, T1b[p * kNS + n * kNY + l], r);
        }
        T2a[j] = a2;
        T2b[j] = b2;
    }
    __syncthreads();
    if (t < kMR) {
        int r = t % kM; int q = (t / kM) % kM; int p = t / (kM * kM);
        float2 t3a = make_float2(0.f, 0.f);
        float2 t3b = make_float2(0.f, 0.f);
        #pragma unroll
        for (int l = 0; l < kNY; ++l) {
            float2 rr = r3s[r * kNY + l];
            cfma(t3a, T2a[(p * kM + q) * kNY + l], rr);
            cfma(t3b, T2b[(p * kM + q) * kNY + l], rr);
        }
        float2 w = wrs[t];
        P[((size_t)(b0 * kC + k) * kC + i) * kMR + t] = cmul(w, t3a);
        P[((size_t)(b1 * kC + k) * kC + i) * kMR + t] = cmul(w, t3b);
    }
}

// K7b: or2[bk][t] = -sum_i P[(bk*16+i)*216+t]
__global__ __launch_bounds__(256) void k_or2red(
    const float2* __restrict__ P, float2* __restrict__ or2)
{
    int id = blockIdx.x * blockDim.x + threadIdx.x;
    if (id >= kB * kC * kMR) return;
    int t = id % kMR; int bk = id / kMR;
    float2 s = make_float2(0.f, 0.f);
    #pragma unroll
    for (int i = 0; i < kC; ++i) {
        float2 v = P[((size_t)bk * kC + i) * kMR + t];
        s.x += v.x; s.y += v.y;
    }
    or2[id] = make_float2(-s.x, -s.y);
}

// ---------------------------------------------------------------------------
// K8a: V[(b,k),(c,p),s] = sum_q ( sum_m or2[b,c,pqm] e3[c,k,m,y] ) e2[c,k,q,x]
// One block per (b,k,c) = 4096. s padded to kVS=256, tail zeroed.
// ---------------------------------------------------------------------------
__global__ __launch_bounds__(256) void k_x2v(
    const float2* __restrict__ or2,
    const float2* __restrict__ e2t, const float2* __restrict__ e3t,
    float2* __restrict__ Vg)
{
    int bid = blockIdx.x;
    int c = bid & 15; int rest = bid >> 4;
    int k = rest & 15; int b = rest >> 4;
    int ck = c * kC + k;
    __shared__ float2 o2s[kMR];
    __shared__ float2 e2s[kM * kNX];
    __shared__ float2 e3s[kM * kNY];
    __shared__ float2 Us[kM * kM * kNY];
    int t = threadIdx.x;
    if (t < kMR) o2s[t] = or2[(size_t)(b * kC + c) * kMR + t];
    if (t < kM * kNX) e2s[t] = e2t[(size_t)ck * (kM * kNX) + t];
    if (t < kM * kNY) e3s[t] = e3t[(size_t)ck * (kM * kNY) + t];
    __syncthreads();
    for (int j = t; j < kM * kM * kNY; j += 256) {
        int y = j % kNY, pq = j / kNY;
        float2 u = make_float2(0.f, 0.f);
        #pragma unroll
        for (int m = 0; m < kM; ++m) cfma(u, o2s[pq * kM + m], e3s[m * kNY + y]);
        Us[j] = u;
    }
    __syncthreads();
    size_t vbase = ((size_t)(b * kC + k) * (kC * kM) + c * kM) * kVS;
    for (int j = t; j < kM * kVS; j += 256) {
        int p = j >> 8, s = j & 255;
        float2 v = make_float2(0.f, 0.f);
        if (s < kNS) {
            int x = s / kNY, y = s % kNY;
            #pragma unroll
            for (int q = 0; q < kM; ++q)
                cfma(v, Us[(p * kM + q) * kNY + y], e2s[q * kNX + x]);
        }
        Vg[vbase + (size_t)p * kVS + s] = v;
    }
}

// ---------------------------------------------------------------------------
// K8b: out[b,k,z,s] = (1/7644) Re( sum_{cp} e1[c,k,p,z] V[(b,k),(c,p),s] )
// grid 768 = bk*3 + zchunk (bk-major: the 3 siblings sharing a V panel are
// adjacent in dispatch order -> same XCD L2). Thread: zt=t>>6, sl=t&63;
// tile 4z x 4s. e1 broadcast from LDS; V coalesced 512B. No s-guard (pad 0).
// ---------------------------------------------------------------------------
__global__ __launch_bounds__(256) void k_x2gemm(
    const float2* __restrict__ Vg, const float2* __restrict__ e1t,
    float* __restrict__ outp)
{
    int bx = blockIdx.x;
    int bk = bx / 3, zc = bx % 3;
    int k = bk & 15;
    int z0 = zc * 13;
    __shared__ float2 e1w[96 * 16];   // [(c,p)][zloc pad16], 12.3 KB
    int t = threadIdx.x;
    for (int j = t; j < 96 * 16; j += 256) {
        int row = j >> 4, zi = j & 15;
        int c = row / kM, p = row % kM;
        float2 e = make_float2(0.f, 0.f);
        if (zi < 13)
            e = e1t[((size_t)(c * kC + k) * kM + p) * kNT + z0 + zi];
        e1w[j] = e;
    }
    __syncthreads();

    int sl = t & 63, zt = t >> 6;
    const float2* vp = Vg + (size_t)bk * (kC * kM) * kVS + sl;
    float acc[4][4];
    #pragma unroll
    for (int zi = 0; zi < 4; ++zi)
        #pragma unroll
        for (int j = 0; j < 4; ++j) acc[zi][j] = 0.f;

    for (int kk = 0; kk < kC * kM; ++kk) {
        float2 vr[4];
        #pragma unroll
        for (int j = 0; j < 4; ++j) vr[j] = vp[(size_t)kk * kVS + 64 * j];
        const int e1base = kk * 16 + zt;
        #pragma unroll
        for (int zi = 0; zi < 4; ++zi) {
            float2 e = e1w[e1base + 4 * zi];
            #pragma unroll
            for (int j = 0; j < 4; ++j)
                acc[zi][j] = fmaf(vr[j].x, e.x, fmaf(-vr[j].y, e.y, acc[zi][j]));
        }
    }

    const float sc = 1.0f / 7644.0f;
    size_t base = (size_t)bk * kNF;
    #pragma unroll
    for (int zi = 0; zi < 4; ++zi) {
        int zloc = zt + 4 * zi;
        if (zloc < 13) {
            size_t zb = base + (size_t)(z0 + zloc) * kNS;
            #pragma unroll
            for (int j = 0; j < 4; ++j) {
                int s = sl + 64 * j;
                if (s < kNS) outp[zb + s] = acc[zi][j] * sc;
            }
        }
    }
}

// ---------------------------------------------------------------------------
extern "C" void kernel_launch(void* const* d_in, const int* in_sizes, int n_in,
                              void* d_out, int out_size, void* d_ws, size_t ws_size,
                              hipStream_t stream) {
    (void)in_sizes; (void)n_in; (void)out_size; (void)ws_size;
    const float* x      = (const float*)d_in[0];
    const float* wp1_re = (const float*)d_in[1];
    const float* wp1_im = (const float*)d_in[2];
    const float* wp2_re = (const float*)d_in[3];
    const float* wp2_im = (const float*)d_in[4];
    const float* wp3_re = (const float*)d_in[5];
    const float* wp3_im = (const float*)d_in[6];
    const float* wr_re  = (const float*)d_in[7];
    const float* wr_im  = (const float*)d_in[8];
    float* out = (float*)d_out;

    const size_t big = (size_t)kNIK * kNF;  // 1,956,864 complex (15.7 MB)
    float2* A   = (float2*)d_ws;            // dft scratch -> or1
    float2* Bb  = A + big;                  // alpha
    float2* Cc  = Bb + big;                 // H -> or2 partials -> t-ifft of or1
    float2* OR2 = Cc + big;                 // 55,296
    float2* r1t = OR2 + (size_t)kB * kC * kMR;
    float2* r2t = r1t + (size_t)kNIK * kM * kNT;
    float2* r3t = r2t + (size_t)kNIK * kM * kNX;
    float2* e1t = r3t + (size_t)kNIK * kM * kNY;
    float2* e2t = e1t + (size_t)kNIK * kM * kNT;
    float2* e3t = e2t + (size_t)kNIK * kM * kNX;
    float2* F39 = e3t + (size_t)kNIK * kM * kNY;
    float2* F14 = F39 + kNT * kNT;
    float2* Vg  = F14 + kNX * kNX;          // dedicated: 256*96*256 complex = 50 MB

    k_init<<<64, 256, 0, stream>>>(wp1_re, wp1_im, wp2_re, wp2_im, wp3_re, wp3_im,
                                   F39, F14, r1t, r2t, r3t, e1t, e2t, e3t);
    // forward DFT: x -> A (t-pass) -> Bb (fused xy). alpha lives in Bb.
    k_dft_t_real<<<dim3(kNIK, 3), 256, 0, stream>>>(x, F39, A);
    k_dft_xy<<<kNIK * kNT, 256, 0, stream>>>(A, F14, Bb);
    // transfer function H -> Cc; or1 -> A
    k_H<<<kNIK, 256, 0, stream>>>(wr_re, wr_im, r1t, r2t, r3t, Cc);
    k_or1<<<kNF / kFCH, 256, 0, stream>>>(Bb, Cc, A);
    // or2: partials into Cc (H dead), reduce -> OR2. Last readers of alpha (Bb).
    k_or2p<<<(kB / 2) * kC * kC, 256, 0, stream>>>(Bb, wr_re, wr_im, r1t, r2t, r3t, Cc);
    k_or2red<<<(kB * kC * kMR + 255) / 256, 256, 0, stream>>>(Cc, OR2);
    // x2: V (dedicated region) then GEMM directly into d_out (overwrite)
    k_x2v<<<kB * kC * kC, 256, 0, stream>>>(OR2, e2t, e3t, Vg);
    k_x2gemm<<<kB * kC * 3, 256, 0, stream>>>(Vg, e1t, out);
    // inverse FFT of or1 (in A): A -> Cc (t-pass; Cc partials dead) -> += out
    k_idft_t<<<dim3(kB * kC, 3), 256, 0, stream>>>(A, F39, Cc);
    k_idft_xy_final<<<kNIK * kNT, 256, 0, stream>>>(Cc, F14, out);
}

// Round 11
// 198.806 us; speedup vs baseline: 1.1472x; 1.0118x over previous
//
#include <hip/hip_runtime.h>

// Problem constants
constexpr int kB  = 16;    // batch
constexpr int kC  = 16;    // CI == CO
constexpr int kM  = 6;     // M1 == M2 == M3
constexpr int kNT = 39;
constexpr int kNX = 14;    // NXr
constexpr int kNY = 14;    // NYr
constexpr int kNS = kNX * kNY;       // 196
constexpr int kNF = kNT * kNS;       // 7644
constexpr int kNIK = kC * kC;        // 256
constexpr int kMR = kM * kM * kM;    // 216
constexpr int kFCH = 6;              // f-chunk for k_or1 (7644 = 6*1274)
constexpr int kVS = 256;             // padded s-stride for V

__device__ __forceinline__ float2 cmul(float2 a, float2 b) {
    return make_float2(a.x * b.x - a.y * b.y, a.x * b.y + a.y * b.x);
}
__device__ __forceinline__ void cfma(float2& c, float2 a, float2 b) {
    c.x = fmaf(a.x, b.x, fmaf(-a.y, b.y, c.x));
    c.y = fmaf(a.x, b.y, fmaf(a.y, b.x, c.y));
}

// ---------------------------------------------------------------------------
// K0: DFT matrices + pole-reciprocal tables r1/r2/r3 + exp tables e1/e2/e3
// ---------------------------------------------------------------------------
__global__ __launch_bounds__(256) void k_init(
    const float* __restrict__ wp1_re, const float* __restrict__ wp1_im,
    const float* __restrict__ wp2_re, const float* __restrict__ wp2_im,
    const float* __restrict__ wp3_re, const float* __restrict__ wp3_im,
    float2* __restrict__ F39, float2* __restrict__ F14,
    float2* __restrict__ r1t, float2* __restrict__ r2t, float2* __restrict__ r3t,
    float2* __restrict__ e1t, float2* __restrict__ e2t, float2* __restrict__ e3t)
{
    const float PI2 = 6.283185307179586f;
    int tid = blockIdx.x * blockDim.x + threadIdx.x;
    int nth = gridDim.x * blockDim.x;

    for (int idx = tid; idx < kNT * kNT; idx += nth) {
        int m = idx / kNT, t = idx % kNT;
        float ang = -PI2 * (float)((m * t) % kNT) / (float)kNT;
        float s, c; sincosf(ang, &s, &c);
        F39[idx] = make_float2(c, s);
    }
    for (int idx = tid; idx < kNX * kNX; idx += nth) {
        int a = idx / kNX, b = idx % kNX;
        float ang = -PI2 * (float)((a * b) % kNX) / (float)kNX;
        float s, c; sincosf(ang, &s, &c);
        F14[idx] = make_float2(c, s);
    }
    for (int idx = tid; idx < kNIK * kM * kNT; idx += nth) {
        int z = idx % kNT; int ikp = idx / kNT;
        float wre = wp1_re[ikp], wim = wp1_im[ikp];
        float f = (z < 20 ? (float)z : (float)(z - kNT)) / (float)kNT;
        float w = PI2 * f;
        float dr = -wre, di = w - wim;
        float inv = 1.0f / (dr * dr + di * di);
        r1t[idx] = make_float2(dr * inv, -di * inv);
        float tt = (float)z;
        float er = expf(wre * tt);
        float s, c; sincosf(wim * tt, &s, &c);
        e1t[idx] = make_float2(er * c, er * s);
    }
    for (int idx = tid; idx < kNIK * kM * kNX; idx += nth) {
        int n = idx % kNX; int ikq = idx / kNX;
        float f = (n <= 6 ? (float)n : (float)(n - kNX)) * 27.0f / 14.0f;
        float w = PI2 * f;
        float tx = (float)n * (1.0f / 27.0f);
        {
            float wre = wp2_re[ikq], wim = wp2_im[ikq];
            float dr = -wre, di = w - wim;
            float inv = 1.0f / (dr * dr + di * di);
            r2t[idx] = make_float2(dr * inv, -di * inv);
            float er = expf(wre * tx);
            float s, c; sincosf(wim * tx, &s, &c);
            e2t[idx] = make_float2(er * c, er * s);
        }
        {
            float wre = wp3_re[ikq], wim = wp3_im[ikq];
            float dr = -wre, di = w - wim;
            float inv = 1.0f / (dr * dr + di * di);
            r3t[idx] = make_float2(dr * inv, -di * inv);
            float er = expf(wre * tx);
            float s, c; sincosf(wim * tx, &s, &c);
            e3t[idx] = make_float2(er * c, er * s);
        }
    }
}

// ---------------------------------------------------------------------------
// Forward t-DFT of real x, register-column form. grid (bc, 3); thread owns s.
// ---------------------------------------------------------------------------
__global__ __launch_bounds__(256) void k_dft_t_real(
    const float* __restrict__ x, const float2* __restrict__ F39, float2* __restrict__ out)
{
    int bc = blockIdx.x, mg = blockIdx.y;
    __shared__ float2 Fs[13 * kNT];
    int t = threadIdx.x;
    for (int j = t; j < 13 * kNT; j += 256)
        Fs[j] = F39[(mg * 13 + j / kNT) * kNT + (j % kNT)];
    __syncthreads();
    if (t < kNS) {
        float col[kNT];
        const float* xp = x + (size_t)bc * kNF + t;
        #pragma unroll
        for (int tt = 0; tt < kNT; ++tt) col[tt] = xp[(size_t)tt * kNS];
        for (int mi = 0; mi < 13; ++mi) {
            float2 acc = make_float2(0.f, 0.f);
            #pragma unroll
            for (int tt = 0; tt < kNT; ++tt) {
                float2 f = Fs[mi * kNT + tt];
                acc.x = fmaf(f.x, col[tt], acc.x);
                acc.y = fmaf(f.y, col[tt], acc.y);
            }
            out[((size_t)bc * kNT + mg * 13 + mi) * kNS + t] = acc;
        }
    }
}

// ---------------------------------------------------------------------------
// Inverse t-DFT (conj F), register-column form. grid (bk, 3); thread owns s.
// ---------------------------------------------------------------------------
__global__ __launch_bounds__(256) void k_idft_t(
    const float2* __restrict__ in, const float2* __restrict__ F39, float2* __restrict__ out)
{
    int bk = blockIdx.x, zg = blockIdx.y;
    __shared__ float2 Fs[13 * kNT];
    int t = threadIdx.x;
    for (int j = t; j < 13 * kNT; j += 256) {
        float2 f = F39[(zg * 13 + j / kNT) * kNT + (j % kNT)];
        f.y = -f.y;
        Fs[j] = f;
    }
    __syncthreads();
    if (t < kNS) {
        float2 col[kNT];
        const float2* ip = in + (size_t)bk * kNF + t;
        #pragma unroll
        for (int m = 0; m < kNT; ++m) col[m] = ip[(size_t)m * kNS];
        for (int zi = 0; zi < 13; ++zi) {
            float2 acc = make_float2(0.f, 0.f);
            #pragma unroll
            for (int m = 0; m < kNT; ++m) cfma(acc, Fs[zi * kNT + m], col[m]);
            out[((size_t)bk * kNT + zg * 13 + zi) * kNS + t] = acc;
        }
    }
}

// ---------------------------------------------------------------------------
// Fused forward x+y DFT on one 14x14 tile. Block per (bc*39+m).
// ---------------------------------------------------------------------------
__global__ __launch_bounds__(256) void k_dft_xy(
    const float2* __restrict__ in, const float2* __restrict__ F14, float2* __restrict__ out)
{
    int bm = blockIdx.x;
    __shared__ float2 tile[kNS];
    __shared__ float2 tmp[kNS];
    __shared__ float2 Fs[kNX * kNX];
    int t = threadIdx.x;
    if (t < kNS) tile[t] = in[(size_t)bm * kNS + t];
    if (t < kNX * kNX) Fs[t] = F14[t];
    __syncthreads();
    if (t < kNS) {
        int n2 = t / kNY, l = t % kNY;
        float2 acc = make_float2(0.f, 0.f);
        #pragma unroll
        for (int n = 0; n < kNX; ++n) cfma(acc, Fs[n2 * kNX + n], tile[n * kNY + l]);
        tmp[t] = acc;
    }
    __syncthreads();
    if (t < kNS) {
        int n = t / kNY, l2 = t % kNY;
        float2 acc = make_float2(0.f, 0.f);
        #pragma unroll
        for (int l = 0; l < kNY; ++l) cfma(acc, Fs[l2 * kNY + l], tmp[n * kNY + l]);
        out[(size_t)bm * kNS + t] = acc;
    }
}

// Fused inverse x+y DFT + take-real + scale + add into output.
__global__ __launch_bounds__(256) void k_idft_xy_final(
    const float2* __restrict__ in, const float2* __restrict__ F14, float* __restrict__ outp)
{
    int bm = blockIdx.x;
    __shared__ float2 tile[kNS];
    __shared__ float2 tmp[kNS];
    __shared__ float2 Fs[kNX * kNX];
    int t = threadIdx.x;
    if (t < kNS) tile[t] = in[(size_t)bm * kNS + t];
    if (t < kNX * kNX) { float2 f = F14[t]; f.y = -f.y; Fs[t] = f; }
    __syncthreads();
    if (t < kNS) {
        int n2 = t / kNY, l = t % kNY;
        float2 acc = make_float2(0.f, 0.f);
        #pragma unroll
        for (int n = 0; n < kNX; ++n) cfma(acc, Fs[n2 * kNX + n], tile[n * kNY + l]);
        tmp[t] = acc;
    }
    __syncthreads();
    if (t < kNS) {
        int n = t / kNY, l2 = t % kNY;
        float2 acc = make_float2(0.f, 0.f);
        #pragma unroll
        for (int l = 0; l < kNY; ++l) cfma(acc, Fs[l2 * kNY + l], tmp[n * kNY + l]);
        outp[(size_t)bm * kNS + t] += acc.x * (1.0f / 7644.0f);
    }
}

// ---------------------------------------------------------------------------
// K4: H[i,k,m,n,l] = sum_{p,q,r} wr[i,k,p,q,r] r1[m] r2[n] r3[l]; block per (i,k)
// ---------------------------------------------------------------------------
__global__ __launch_bounds__(256) void k_H(
    const float* __restrict__ wr_re, const float* __restrict__ wr_im,
    const float2* __restrict__ r1t, const float2* __restrict__ r2t,
    const float2* __restrict__ r3t, float2* __restrict__ H)
{
    int ik = blockIdx.x;
    __shared__ float2 wrs[kMR];
    __shared__ float2 r1s[kM * kNT];
    __shared__ float2 r2s[kM * kNX];
    __shared__ float2 r3s[kM * kNY];
    __shared__ float2 As[kM * kM * kNY];
    __shared__ float2 Ss[kM * kNS];
    int t = threadIdx.x;
    for (int j = t; j < kMR; j += 256)
        wrs[j] = make_float2(wr_re[ik * kMR + j], wr_im[ik * kMR + j]);
    for (int j = t; j < kM * kNT; j += 256) r1s[j] = r1t[(size_t)ik * kM * kNT + j];
    for (int j = t; j < kM * kNX; j += 256) r2s[j] = r2t[(size_t)ik * kM * kNX + j];
    for (int j = t; j < kM * kNY; j += 256) r3s[j] = r3t[(size_t)ik * kM * kNY + j];
    __syncthreads();
    for (int j = t; j < kM * kM * kNY; j += 256) {
        int l = j % kNY; int pq = j / kNY;
        float2 acc = make_float2(0.f, 0.f);
        #pragma unroll
        for (int r = 0; r < kM; ++r) cfma(acc, wrs[pq * kM + r], r3s[r * kNY + l]);
        As[j] = acc;
    }
    __syncthreads();
    for (int j = t; j < kM * kNS; j += 256) {
        int l = j % kNY; int n = (j / kNY) % kNX; int p = j / kNS;
        float2 acc = make_float2(0.f, 0.f);
        #pragma unroll
        for (int q = 0; q < kM; ++q) cfma(acc, r2s[q * kNX + n], As[(p * kM + q) * kNY + l]);
        Ss[j] = acc;
    }
    __syncthreads();
    for (int j = t; j < kNF; j += 256) {
        int m = j / kNS; int nl = j % kNS;
        float2 acc = make_float2(0.f, 0.f);
        #pragma unroll
        for (int p = 0; p < kM; ++p) cfma(acc, r1s[p * kNT + m], Ss[p * kNS + nl]);
        H[(size_t)ik * kNF + j] = acc;
    }
}

// ---------------------------------------------------------------------------
// K5: or1[b,k,f] = sum_i alpha[b,i,f] * H[i,k,f]
// f-chunked, LDS-staged (16x reuse). One block per 6 f's; thread = (b,k).
// ---------------------------------------------------------------------------
__global__ __launch_bounds__(256) void k_or1(
    const float2* __restrict__ alpha, const float2* __restrict__ H, float2* __restrict__ out)
{
    int f0 = blockIdx.x * kFCH;
    __shared__ float2 As[256 * 7 + 16];
    __shared__ float2 Hs[256 * 7 + 16];
    int t = threadIdx.x;
    {
        const float2* ap = alpha + (size_t)t * kNF + f0;
        const float2* hp = H + (size_t)t * kNF + f0;
        int base = t * 7 + (t >> 4);
        #pragma unroll
        for (int j = 0; j < kFCH; ++j) {
            As[base + j] = ap[j];
            Hs[base + j] = hp[j];
        }
    }
    __syncthreads();
    int b = t >> 4, k = t & 15;
    float2 acc[kFCH];
    #pragma unroll
    for (int j = 0; j < kFCH; ++j) acc[j] = make_float2(0.f, 0.f);
    #pragma unroll
    for (int i = 0; i < kC; ++i) {
        int ai = (b * 16 + i) * 7 + b;
        int hi = (i * 16 + k) * 7 + i;
        #pragma unroll
        for (int j = 0; j < kFCH; ++j) cfma(acc[j], As[ai + j], Hs[hi + j]);
    }
    float2* op = out + (size_t)t * kNF + f0;
    #pragma unroll
    for (int j = 0; j < kFCH; ++j) op[j] = acc[j];
}

// ---------------------------------------------------------------------------
// K7a: partial or2 per (b-pair,k,i). Tables (ik) amortized across 2 batches.
// P[((b*16+k)*16+i)*216+t] = wr[ik,t] * G[b,i,k,t]
// ---------------------------------------------------------------------------
__global__ __launch_bounds__(256) void k_or2p(
    const float2* __restrict__ alpha,
    const float* __restrict__ wr_re, const float* __restrict__ wr_im,
    const float2* __restrict__ r1t, const float2* __restrict__ r2t,
    const float2* __restrict__ r3t, float2* __restrict__ P)
{
    int blk = blockIdx.x;            // (pb*16 + k)*16 + i
    int i = blk % kC; int rest = blk / kC;
    int k = rest % kC; int pb = rest / kC;
    int b0 = 2 * pb, b1 = 2 * pb + 1;
    int ik = i * kC + k;
    __shared__ float2 r1s[kM * kNT];
    __shared__ float2 r2s[kM * kNX];
    __shared__ float2 r3s[kM * kNY];
    __shared__ float2 wrs[kMR];
    __shared__ float2 T1a[kM * kNS];
    __shared__ float2 T1b[kM * kNS];
    __shared__ float2 T2a[kM * kM * kNY];
    __shared__ float2 T2b[kM * kM * kNY];
    int t = threadIdx.x;
    for (int j = t; j < kM * kNT; j += 256) r1s[j] = r1t[(size_t)ik * kM * kNT + j];
    for (int j = t; j < kM * kNX; j += 256) r2s[j] = r2t[(size_t)ik * kM * kNX + j];
    for (int j = t; j < kM * kNY; j += 256) r3s[j] = r3t[(size_t)ik * kM * kNY + j];
    for (int j = t; j < kMR; j += 256)
        wrs[j] = make_float2(wr_re[ik * kMR + j], wr_im[ik * kMR + j]);
    __syncthreads();
    if (t < kNS) {
        float2 c0 = make_float2(0.f, 0.f), c1 = c0, c2 = c0, c3 = c0, c4 = c0, c5 = c0;
        float2 d0 = c0, d1 = c0, d2 = c0, d3 = c0, d4 = c0, d5 = c0;
        const float2* ap0 = alpha + (size_t)(b0 * kC + i) * kNF + t;
        const float2* ap1 = alpha + (size_t)(b1 * kC + i) * kNF + t;
        for (int m = 0; m < kNT; ++m) {
            float2 a0 = ap0[(size_t)m * kNS];
            float2 a1 = ap1[(size_t)m * kNS];
            float2 r;
            r = r1s[0 * kNT + m]; cfma(c0, a0, r); cfma(d0, a1, r);
            r = r1s[1 * kNT + m]; cfma(c1, a0, r); cfma(d1, a1, r);
            r = r1s[2 * kNT + m]; cfma(c2, a0, r); cfma(d2, a1, r);
            r = r1s[3 * kNT + m]; cfma(c3, a0, r); cfma(d3, a1, r);
            r = r1s[4 * kNT + m]; cfma(c4, a0, r); cfma(d4, a1, r);
            r = r1s[5 * kNT + m]; cfma(c5, a0, r); cfma(d5, a1, r);
        }
        T1a[0 * kNS + t] = c0; T1a[1 * kNS + t] = c1; T1a[2 * kNS + t] = c2;
        T1a[3 * kNS + t] = c3; T1a[4 * kNS + t] = c4; T1a[5 * kNS + t] = c5;
        T1b[0 * kNS + t] = d0; T1b[1 * kNS + t] = d1; T1b[2 * kNS + t] = d2;
        T1b[3 * kNS + t] = d3; T1b[4 * kNS + t] = d4; T1b[5 * kNS + t] = d5;
    }
    __syncthreads();
    for (int j = t; j < kM * kM * kNY; j += 256) {
        int l = j % kNY; int q = (j / kNY) % kM; int p = j / (kNY * kM);
        float2 a2 = make_float2(0.f, 0.f);
        float2 b2 = make_float2(0.f, 0.f);
        #pragma unroll
        for (int n = 0; n < kNX; ++n) {
            float2 r = r2s[q * kNX + n];
            cfma(a2, T1a[p * kNS + n * kNY + l], r);
            cfma(b2, T1b[p * kNS + n * kNY + l], r);
        }
        T2a[j] = a2;
        T2b[j] = b2;
    }
    __syncthreads();
    if (t < kMR) {
        int r = t % kM; int q = (t / kM) % kM; int p = t / (kM * kM);
        float2 t3a = make_float2(0.f, 0.f);
        float2 t3b = make_float2(0.f, 0.f);
        #pragma unroll
        for (int l = 0; l < kNY; ++l) {
            float2 rr = r3s[r * kNY + l];
            cfma(t3a, T2a[(p * kM + q) * kNY + l], rr);
            cfma(t3b, T2b[(p * kM + q) * kNY + l], rr);
        }
        float2 w = wrs[t];
        P[((size_t)(b0 * kC + k) * kC + i) * kMR + t] = cmul(w, t3a);
        P[((size_t)(b1 * kC + k) * kC + i) * kMR + t] = cmul(w, t3b);
    }
}

// K7b: or2[bk][t] = -sum_i P[(bk*16+i)*216+t]
__global__ __launch_bounds__(256) void k_or2red(
    const float2* __restrict__ P, float2* __restrict__ or2)
{
    int id = blockIdx.x * blockDim.x + threadIdx.x;
    if (id >= kB * kC * kMR) return;
    int t = id % kMR; int bk = id / kMR;
    float2 s = make_float2(0.f, 0.f);
    #pragma unroll
    for (int i = 0; i < kC; ++i) {
        float2 v = P[((size_t)bk * kC + i) * kMR + t];
        s.x += v.x; s.y += v.y;
    }
    or2[id] = make_float2(-s.x, -s.y);
}

// ---------------------------------------------------------------------------
// K8a: V[(b,k),(c,p),s] = sum_q ( sum_m or2[b,c,pqm] e3[c,k,m,y] ) e2[c,k,q,x]
// One block per (b,k,c) = 4096. s padded to kVS=256, tail zeroed.
// ---------------------------------------------------------------------------
__global__ __launch_bounds__(256) void k_x2v(
    const float2* __restrict__ or2,
    const float2* __restrict__ e2t, const float2* __restrict__ e3t,
    float2* __restrict__ Vg)
{
    int bid = blockIdx.x;
    int c = bid & 15; int rest = bid >> 4;
    int k = rest & 15; int b = rest >> 4;
    int ck = c * kC + k;
    __shared__ float2 o2s[kMR];
    __shared__ float2 e2s[kM * kNX];
    __shared__ float2 e3s[kM * kNY];
    __shared__ float2 Us[kM * kM * kNY];
    int t = threadIdx.x;
    if (t < kMR) o2s[t] = or2[(size_t)(b * kC + c) * kMR + t];
    if (t < kM * kNX) e2s[t] = e2t[(size_t)ck * (kM * kNX) + t];
    if (t < kM * kNY) e3s[t] = e3t[(size_t)ck * (kM * kNY) + t];
    __syncthreads();
    for (int j = t; j < kM * kM * kNY; j += 256) {
        int y = j % kNY, pq = j / kNY;
        float2 u = make_float2(0.f, 0.f);
        #pragma unroll
        for (int m = 0; m < kM; ++m) cfma(u, o2s[pq * kM + m], e3s[m * kNY + y]);
        Us[j] = u;
    }
    __syncthreads();
    size_t vbase = ((size_t)(b * kC + k) * (kC * kM) + c * kM) * kVS;
    for (int j = t; j < kM * kVS; j += 256) {
        int p = j >> 8, s = j & 255;
        float2 v = make_float2(0.f, 0.f);
        if (s < kNS) {
            int x = s / kNY, y = s % kNY;
            #pragma unroll
            for (int q = 0; q < kM; ++q)
                cfma(v, Us[(p * kM + q) * kNY + y], e2s[q * kNX + x]);
        }
        Vg[vbase + (size_t)p * kVS + s] = v;
    }
}

// ---------------------------------------------------------------------------
// K8b: out[b,k,z,s] = (1/7644) Re( sum_{cp} e1[c,k,p,z] V[(b,k),(c,p),s] )
// grid 768, zc-major: bx = zc*256 + bk, so the 3 siblings sharing a V panel
// are all ≡ bk (mod 8) -> SAME XCD L2 (blocks round-robin across 8 XCDs).
// Thread: zt=t>>6, sl=t&63; tile 4z x 4s. Explicit 2-deep V prefetch
// (named register sets, compile-time indexed) to double outstanding loads.
// ---------------------------------------------------------------------------
__global__ __launch_bounds__(256) void k_x2gemm(
    const float2* __restrict__ Vg, const float2* __restrict__ e1t,
    float* __restrict__ outp)
{
    int bx = blockIdx.x;
    int bk = bx & 255, zc = bx >> 8;
    int k = bk & 15;
    int z0 = zc * 13;
    __shared__ float2 e1w[96 * 16];   // [(c,p)][zloc pad16], 12.3 KB
    int t = threadIdx.x;
    for (int j = t; j < 96 * 16; j += 256) {
        int row = j >> 4, zi = j & 15;
        int c = row / kM, p = row % kM;
        float2 e = make_float2(0.f, 0.f);
        if (zi < 13)
            e = e1t[((size_t)(c * kC + k) * kM + p) * kNT + z0 + zi];
        e1w[j] = e;
    }
    __syncthreads();

    int sl = t & 63, zt = t >> 6;
    const float2* vp = Vg + (size_t)bk * (kC * kM) * kVS + sl;
    float acc[4][4];
    #pragma unroll
    for (int zi = 0; zi < 4; ++zi)
        #pragma unroll
        for (int j = 0; j < 4; ++j) acc[zi][j] = 0.f;

    // 2-deep software pipeline over kk (96 steps, manually unrolled by 2)
    float2 vrA[4], vrB[4];
    #pragma unroll
    for (int j = 0; j < 4; ++j) vrA[j] = vp[64 * j];
    for (int kk = 0; kk < 96; kk += 2) {
        // prefetch kk+1 into B
        #pragma unroll
        for (int j = 0; j < 4; ++j) vrB[j] = vp[(size_t)(kk + 1) * kVS + 64 * j];
        {
            const int e1base = kk * 16 + zt;
            #pragma unroll
            for (int zi = 0; zi < 4; ++zi) {
                float2 e = e1w[e1base + 4 * zi];
                #pragma unroll
                for (int j = 0; j < 4; ++j)
                    acc[zi][j] = fmaf(vrA[j].x, e.x, fmaf(-vrA[j].y, e.y, acc[zi][j]));
            }
        }
        // prefetch kk+2 into A
        if (kk + 2 < 96) {
            #pragma unroll
            for (int j = 0; j < 4; ++j) vrA[j] = vp[(size_t)(kk + 2) * kVS + 64 * j];
        }
        {
            const int e1base = (kk + 1) * 16 + zt;
            #pragma unroll
            for (int zi = 0; zi < 4; ++zi) {
                float2 e = e1w[e1base + 4 * zi];
                #pragma unroll
                for (int j = 0; j < 4; ++j)
                    acc[zi][j] = fmaf(vrB[j].x, e.x, fmaf(-vrB[j].y, e.y, acc[zi][j]));
            }
        }
    }

    const float sc = 1.0f / 7644.0f;
    size_t base = (size_t)bk * kNF;
    #pragma unroll
    for (int zi = 0; zi < 4; ++zi) {
        int zloc = zt + 4 * zi;
        if (zloc < 13) {
            size_t zb = base + (size_t)(z0 + zloc) * kNS;
            #pragma unroll
            for (int j = 0; j < 4; ++j) {
                int s = sl + 64 * j;
                if (s < kNS) outp[zb + s] = acc[zi][j] * sc;
            }
        }
    }
}

// ---------------------------------------------------------------------------
extern "C" void kernel_launch(void* const* d_in, const int* in_sizes, int n_in,
                              void* d_out, int out_size, void* d_ws, size_t ws_size,
                              hipStream_t stream) {
    (void)in_sizes; (void)n_in; (void)out_size; (void)ws_size;
    const float* x      = (const float*)d_in[0];
    const float* wp1_re = (const float*)d_in[1];
    const float* wp1_im = (const float*)d_in[2];
    const float* wp2_re = (const float*)d_in[3];
    const float* wp2_im = (const float*)d_in[4];
    const float* wp3_re = (const float*)d_in[5];
    const float* wp3_im = (const float*)d_in[6];
    const float* wr_re  = (const float*)d_in[7];
    const float* wr_im  = (const float*)d_in[8];
    float* out = (float*)d_out;

    const size_t big = (size_t)kNIK * kNF;  // 1,956,864 complex (15.7 MB)
    float2* A   = (float2*)d_ws;            // dft scratch -> or1
    float2* Bb  = A + big;                  // alpha
    float2* Cc  = Bb + big;                 // H -> or2 partials -> t-ifft of or1
    float2* OR2 = Cc + big;                 // 55,296
    float2* r1t = OR2 + (size_t)kB * kC * kMR;
    float2* r2t = r1t + (size_t)kNIK * kM * kNT;
    float2* r3t = r2t + (size_t)kNIK * kM * kNX;
    float2* e1t = r3t + (size_t)kNIK * kM * kNY;
    float2* e2t = e1t + (size_t)kNIK * kM * kNT;
    float2* e3t = e2t + (size_t)kNIK * kM * kNX;
    float2* F39 = e3t + (size_t)kNIK * kM * kNY;
    float2* F14 = F39 + kNT * kNT;
    float2* Vg  = F14 + kNX * kNX;          // dedicated: 256*96*256 complex = 50 MB

    k_init<<<64, 256, 0, stream>>>(wp1_re, wp1_im, wp2_re, wp2_im, wp3_re, wp3_im,
                                   F39, F14, r1t, r2t, r3t, e1t, e2t, e3t);
    // forward DFT: x -> A (t-pass) -> Bb (fused xy). alpha lives in Bb.
    k_dft_t_real<<<dim3(kNIK, 3), 256, 0, stream>>>(x, F39, A);
    k_dft_xy<<<kNIK * kNT, 256, 0, stream>>>(A, F14, Bb);
    // transfer function H -> Cc; or1 -> A
    k_H<<<kNIK, 256, 0, stream>>>(wr_re, wr_im, r1t, r2t, r3t, Cc);
    k_or1<<<kNF / kFCH, 256, 0, stream>>>(Bb, Cc, A);
    // or2: partials into Cc (H dead), reduce -> OR2. Last readers of alpha (Bb).
    k_or2p<<<(kB / 2) * kC * kC, 256, 0, stream>>>(Bb, wr_re, wr_im, r1t, r2t, r3t, Cc);
    k_or2red<<<(kB * kC * kMR + 255) / 256, 256, 0, stream>>>(Cc, OR2);
    // x2: V (dedicated region) then GEMM directly into d_out (overwrite)
    k_x2v<<<kB * kC * kC, 256, 0, stream>>>(OR2, e2t, e3t, Vg);
    k_x2gemm<<<kB * kC * 3, 256, 0, stream>>>(Vg, e1t, out);
    // inverse FFT of or1 (in A): A -> Cc (t-pass; Cc partials dead) -> += out
    k_idft_t<<<dim3(kB * kC, 3), 256, 0, stream>>>(A, F39, Cc);
    k_idft_xy_final<<<kNIK * kNT, 256, 0, stream>>>(Cc, F14, out);
}

// Round 13
// 191.943 us; speedup vs baseline: 1.1882x; 1.0358x over previous
//
#include <hip/hip_runtime.h>

// Problem constants
constexpr int kB  = 16;    // batch
constexpr int kC  = 16;    // CI == CO
constexpr int kM  = 6;     // M1 == M2 == M3
constexpr int kNT = 39;
constexpr int kNX = 14;    // NXr
constexpr int kNY = 14;    // NYr
constexpr int kNS = kNX * kNY;       // 196
constexpr int kNF = kNT * kNS;       // 7644
constexpr int kNIK = kC * kC;        // 256
constexpr int kMR = kM * kM * kM;    // 216
constexpr int kFCH = 6;              // f-chunk for k_or1 (7644 = 6*1274)
constexpr int kVS = 256;             // padded s-stride for V

__device__ __forceinline__ float2 cmul(float2 a, float2 b) {
    return make_float2(a.x * b.x - a.y * b.y, a.x * b.y + a.y * b.x);
}
__device__ __forceinline__ void cfma(float2& c, float2 a, float2 b) {
    c.x = fmaf(a.x, b.x, fmaf(-a.y, b.y, c.x));
    c.y = fmaf(a.x, b.y, fmaf(a.y, b.x, c.y));
}

// ---------------------------------------------------------------------------
// K0: DFT matrices + pole-reciprocal tables r1/r2/r3 + exp tables e1/e2/e3
// ---------------------------------------------------------------------------
__global__ __launch_bounds__(256) void k_init(
    const float* __restrict__ wp1_re, const float* __restrict__ wp1_im,
    const float* __restrict__ wp2_re, const float* __restrict__ wp2_im,
    const float* __restrict__ wp3_re, const float* __restrict__ wp3_im,
    float2* __restrict__ F39, float2* __restrict__ F14,
    float2* __restrict__ r1t, float2* __restrict__ r2t, float2* __restrict__ r3t,
    float2* __restrict__ e1t, float2* __restrict__ e2t, float2* __restrict__ e3t)
{
    const float PI2 = 6.283185307179586f;
    int tid = blockIdx.x * blockDim.x + threadIdx.x;
    int nth = gridDim.x * blockDim.x;

    for (int idx = tid; idx < kNT * kNT; idx += nth) {
        int m = idx / kNT, t = idx % kNT;
        float ang = -PI2 * (float)((m * t) % kNT) / (float)kNT;
        float s, c; sincosf(ang, &s, &c);
        F39[idx] = make_float2(c, s);
    }
    for (int idx = tid; idx < kNX * kNX; idx += nth) {
        int a = idx / kNX, b = idx % kNX;
        float ang = -PI2 * (float)((a * b) % kNX) / (float)kNX;
        float s, c; sincosf(ang, &s, &c);
        F14[idx] = make_float2(c, s);
    }
    for (int idx = tid; idx < kNIK * kM * kNT; idx += nth) {
        int z = idx % kNT; int ikp = idx / kNT;
        float wre = wp1_re[ikp], wim = wp1_im[ikp];
        float f = (z < 20 ? (float)z : (float)(z - kNT)) / (float)kNT;
        float w = PI2 * f;
        float dr = -wre, di = w - wim;
        float inv = 1.0f / (dr * dr + di * di);
        r1t[idx] = make_float2(dr * inv, -di * inv);
        float tt = (float)z;
        float er = expf(wre * tt);
        float s, c; sincosf(wim * tt, &s, &c);
        e1t[idx] = make_float2(er * c, er * s);
    }
    for (int idx = tid; idx < kNIK * kM * kNX; idx += nth) {
        int n = idx % kNX; int ikq = idx / kNX;
        float f = (n <= 6 ? (float)n : (float)(n - kNX)) * 27.0f / 14.0f;
        float w = PI2 * f;
        float tx = (float)n * (1.0f / 27.0f);
        {
            float wre = wp2_re[ikq], wim = wp2_im[ikq];
            float dr = -wre, di = w - wim;
            float inv = 1.0f / (dr * dr + di * di);
            r2t[idx] = make_float2(dr * inv, -di * inv);
            float er = expf(wre * tx);
            float s, c; sincosf(wim * tx, &s, &c);
            e2t[idx] = make_float2(er * c, er * s);
        }
        {
            float wre = wp3_re[ikq], wim = wp3_im[ikq];
            float dr = -wre, di = w - wim;
            float inv = 1.0f / (dr * dr + di * di);
            r3t[idx] = make_float2(dr * inv, -di * inv);
            float er = expf(wre * tx);
            float s, c; sincosf(wim * tx, &s, &c);
            e3t[idx] = make_float2(er * c, er * s);
        }
    }
}

// ---------------------------------------------------------------------------
// Forward t-DFT of real x, register-column form. grid (bc, 3); thread owns s.
// ---------------------------------------------------------------------------
__global__ __launch_bounds__(256) void k_dft_t_real(
    const float* __restrict__ x, const float2* __restrict__ F39, float2* __restrict__ out)
{
    int bc = blockIdx.x, mg = blockIdx.y;
    __shared__ float2 Fs[13 * kNT];
    int t = threadIdx.x;
    for (int j = t; j < 13 * kNT; j += 256)
        Fs[j] = F39[(mg * 13 + j / kNT) * kNT + (j % kNT)];
    __syncthreads();
    if (t < kNS) {
        float col[kNT];
        const float* xp = x + (size_t)bc * kNF + t;
        #pragma unroll
        for (int tt = 0; tt < kNT; ++tt) col[tt] = xp[(size_t)tt * kNS];
        for (int mi = 0; mi < 13; ++mi) {
            float2 acc = make_float2(0.f, 0.f);
            #pragma unroll
            for (int tt = 0; tt < kNT; ++tt) {
                float2 f = Fs[mi * kNT + tt];
                acc.x = fmaf(f.x, col[tt], acc.x);
                acc.y = fmaf(f.y, col[tt], acc.y);
            }
            out[((size_t)bc * kNT + mg * 13 + mi) * kNS + t] = acc;
        }
    }
}

// ---------------------------------------------------------------------------
// Inverse t-DFT (conj F), register-column form. grid (bk, 3); thread owns s.
// ---------------------------------------------------------------------------
__global__ __launch_bounds__(256) void k_idft_t(
    const float2* __restrict__ in, const float2* __restrict__ F39, float2* __restrict__ out)
{
    int bk = blockIdx.x, zg = blockIdx.y;
    __shared__ float2 Fs[13 * kNT];
    int t = threadIdx.x;
    for (int j = t; j < 13 * kNT; j += 256) {
        float2 f = F39[(zg * 13 + j / kNT) * kNT + (j % kNT)];
        f.y = -f.y;
        Fs[j] = f;
    }
    __syncthreads();
    if (t < kNS) {
        float2 col[kNT];
        const float2* ip = in + (size_t)bk * kNF + t;
        #pragma unroll
        for (int m = 0; m < kNT; ++m) col[m] = ip[(size_t)m * kNS];
        for (int zi = 0; zi < 13; ++zi) {
            float2 acc = make_float2(0.f, 0.f);
            #pragma unroll
            for (int m = 0; m < kNT; ++m) cfma(acc, Fs[zi * kNT + m], col[m]);
            out[((size_t)bk * kNT + zg * 13 + zi) * kNS + t] = acc;
        }
    }
}

// ---------------------------------------------------------------------------
// Fused forward x+y DFT on one 14x14 tile. Block per (bc*39+m).
// ---------------------------------------------------------------------------
__global__ __launch_bounds__(256) void k_dft_xy(
    const float2* __restrict__ in, const float2* __restrict__ F14, float2* __restrict__ out)
{
    int bm = blockIdx.x;
    __shared__ float2 tile[kNS];
    __shared__ float2 tmp[kNS];
    __shared__ float2 Fs[kNX * kNX];
    int t = threadIdx.x;
    if (t < kNS) tile[t] = in[(size_t)bm * kNS + t];
    if (t < kNX * kNX) Fs[t] = F14[t];
    __syncthreads();
    if (t < kNS) {
        int n2 = t / kNY, l = t % kNY;
        float2 acc = make_float2(0.f, 0.f);
        #pragma unroll
        for (int n = 0; n < kNX; ++n) cfma(acc, Fs[n2 * kNX + n], tile[n * kNY + l]);
        tmp[t] = acc;
    }
    __syncthreads();
    if (t < kNS) {
        int n = t / kNY, l2 = t % kNY;
        float2 acc = make_float2(0.f, 0.f);
        #pragma unroll
        for (int l = 0; l < kNY; ++l) cfma(acc, Fs[l2 * kNY + l], tmp[n * kNY + l]);
        out[(size_t)bm * kNS + t] = acc;
    }
}

// Fused inverse x+y DFT + take-real + scale + add into output.
__global__ __launch_bounds__(256) void k_idft_xy_final(
    const float2* __restrict__ in, const float2* __restrict__ F14, float* __restrict__ outp)
{
    int bm = blockIdx.x;
    __shared__ float2 tile[kNS];
    __shared__ float2 tmp[kNS];
    __shared__ float2 Fs[kNX * kNX];
    int t = threadIdx.x;
    if (t < kNS) tile[t] = in[(size_t)bm * kNS + t];
    if (t < kNX * kNX) { float2 f = F14[t]; f.y = -f.y; Fs[t] = f; }
    __syncthreads();
    if (t < kNS) {
        int n2 = t / kNY, l = t % kNY;
        float2 acc = make_float2(0.f, 0.f);
        #pragma unroll
        for (int n = 0; n < kNX; ++n) cfma(acc, Fs[n2 * kNX + n], tile[n * kNY + l]);
        tmp[t] = acc;
    }
    __syncthreads();
    if (t < kNS) {
        int n = t / kNY, l2 = t % kNY;
        float2 acc = make_float2(0.f, 0.f);
        #pragma unroll
        for (int l = 0; l < kNY; ++l) cfma(acc, Fs[l2 * kNY + l], tmp[n * kNY + l]);
        outp[(size_t)bm * kNS + t] += acc.x * (1.0f / 7644.0f);
    }
}

// ---------------------------------------------------------------------------
// K4: H[i,k,m,n,l] = sum_{p,q,r} wr[i,k,p,q,r] r1[m] r2[n] r3[l]; block per (i,k)
// ---------------------------------------------------------------------------
__global__ __launch_bounds__(256) void k_H(
    const float* __restrict__ wr_re, const float* __restrict__ wr_im,
    const float2* __restrict__ r1t, const float2* __restrict__ r2t,
    const float2* __restrict__ r3t, float2* __restrict__ H)
{
    int ik = blockIdx.x;
    __shared__ float2 wrs[kMR];
    __shared__ float2 r1s[kM * kNT];
    __shared__ float2 r2s[kM * kNX];
    __shared__ float2 r3s[kM * kNY];
    __shared__ float2 As[kM * kM * kNY];
    __shared__ float2 Ss[kM * kNS];
    int t = threadIdx.x;
    for (int j = t; j < kMR; j += 256)
        wrs[j] = make_float2(wr_re[ik * kMR + j], wr_im[ik * kMR + j]);
    for (int j = t; j < kM * kNT; j += 256) r1s[j] = r1t[(size_t)ik * kM * kNT + j];
    for (int j = t; j < kM * kNX; j += 256) r2s[j] = r2t[(size_t)ik * kM * kNX + j];
    for (int j = t; j < kM * kNY; j += 256) r3s[j] = r3t[(size_t)ik * kM * kNY + j];
    __syncthreads();
    for (int j = t; j < kM * kM * kNY; j += 256) {
        int l = j % kNY; int pq = j / kNY;
        float2 acc = make_float2(0.f, 0.f);
        #pragma unroll
        for (int r = 0; r < kM; ++r) cfma(acc, wrs[pq * kM + r], r3s[r * kNY + l]);
        As[j] = acc;
    }
    __syncthreads();
    for (int j = t; j < kM * kNS; j += 256) {
        int l = j % kNY; int n = (j / kNY) % kNX; int p = j / kNS;
        float2 acc = make_float2(0.f, 0.f);
        #pragma unroll
        for (int q = 0; q < kM; ++q) cfma(acc, r2s[q * kNX + n], As[(p * kM + q) * kNY + l]);
        Ss[j] = acc;
    }
    __syncthreads();
    for (int j = t; j < kNF; j += 256) {
        int m = j / kNS; int nl = j % kNS;
        float2 acc = make_float2(0.f, 0.f);
        #pragma unroll
        for (int p = 0; p < kM; ++p) cfma(acc, r1s[p * kNT + m], Ss[p * kNS + nl]);
        H[(size_t)ik * kNF + j] = acc;
    }
}

// ---------------------------------------------------------------------------
// K5: or1[b,k,f] = sum_i alpha[b,i,f] * H[i,k,f]
// f-chunked, LDS-staged (16x reuse). One block per 6 f's; thread = (b,k).
// ---------------------------------------------------------------------------
__global__ __launch_bounds__(256) void k_or1(
    const float2* __restrict__ alpha, const float2* __restrict__ H, float2* __restrict__ out)
{
    int f0 = blockIdx.x * kFCH;
    __shared__ float2 As[256 * 7 + 16];
    __shared__ float2 Hs[256 * 7 + 16];
    int t = threadIdx.x;
    {
        const float2* ap = alpha + (size_t)t * kNF + f0;
        const float2* hp = H + (size_t)t * kNF + f0;
        int base = t * 7 + (t >> 4);
        #pragma unroll
        for (int j = 0; j < kFCH; ++j) {
            As[base + j] = ap[j];
            Hs[base + j] = hp[j];
        }
    }
    __syncthreads();
    int b = t >> 4, k = t & 15;
    float2 acc[kFCH];
    #pragma unroll
    for (int j = 0; j < kFCH; ++j) acc[j] = make_float2(0.f, 0.f);
    #pragma unroll
    for (int i = 0; i < kC; ++i) {
        int ai = (b * 16 + i) * 7 + b;
        int hi = (i * 16 + k) * 7 + i;
        #pragma unroll
        for (int j = 0; j < kFCH; ++j) cfma(acc[j], As[ai + j], Hs[hi + j]);
    }
    float2* op = out + (size_t)t * kNF + f0;
    #pragma unroll
    for (int j = 0; j < kFCH; ++j) op[j] = acc[j];
}

// ---------------------------------------------------------------------------
// K7a: partial or2 per (b-pair,k,i). Tables (ik) amortized across 2 batches.
// P[((b*16+k)*16+i)*216+t] = wr[ik,t] * G[b,i,k,t]
// ---------------------------------------------------------------------------
__global__ __launch_bounds__(256) void k_or2p(
    const float2* __restrict__ alpha,
    const float* __restrict__ wr_re, const float* __restrict__ wr_im,
    const float2* __restrict__ r1t, const float2* __restrict__ r2t,
    const float2* __restrict__ r3t, float2* __restrict__ P)
{
    int blk = blockIdx.x;            // (pb*16 + k)*16 + i
    int i = blk % kC; int rest = blk / kC;
    int k = rest % kC; int pb = rest / kC;
    int b0 = 2 * pb, b1 = 2 * pb + 1;
    int ik = i * kC + k;
    __shared__ float2 r1s[kM * kNT];
    __shared__ float2 r2s[kM * kNX];
    __shared__ float2 r3s[kM * kNY];
    __shared__ float2 wrs[kMR];
    __shared__ float2 T1a[kM * kNS];
    __shared__ float2 T1b[kM * kNS];
    __shared__ float2 T2a[kM * kM * kNY];
    __shared__ float2 T2b[kM * kM * kNY];
    int t = threadIdx.x;
    for (int j = t; j < kM * kNT; j += 256) r1s[j] = r1t[(size_t)ik * kM * kNT + j];
    for (int j = t; j < kM * kNX; j += 256) r2s[j] = r2t[(size_t)ik * kM * kNX + j];
    for (int j = t; j < kM * kNY; j += 256) r3s[j] = r3t[(size_t)ik * kM * kNY + j];
    for (int j = t; j < kMR; j += 256)
        wrs[j] = make_float2(wr_re[ik * kMR + j], wr_im[ik * kMR + j]);
    __syncthreads();
    if (t < kNS) {
        float2 c0 = make_float2(0.f, 0.f), c1 = c0, c2 = c0, c3 = c0, c4 = c0, c5 = c0;
        float2 d0 = c0, d1 = c0, d2 = c0, d3 = c0, d4 = c0, d5 = c0;
        const float2* ap0 = alpha + (size_t)(b0 * kC + i) * kNF + t;
        const float2* ap1 = alpha + (size_t)(b1 * kC + i) * kNF + t;
        for (int m = 0; m < kNT; ++m) {
            float2 a0 = ap0[(size_t)m * kNS];
            float2 a1 = ap1[(size_t)m * kNS];
            float2 r;
            r = r1s[0 * kNT + m]; cfma(c0, a0, r); cfma(d0, a1, r);
            r = r1s[1 * kNT + m]; cfma(c1, a0, r); cfma(d1, a1, r);
            r = r1s[2 * kNT + m]; cfma(c2, a0, r); cfma(d2, a1, r);
            r = r1s[3 * kNT + m]; cfma(c3, a0, r); cfma(d3, a1, r);
            r = r1s[4 * kNT + m]; cfma(c4, a0, r); cfma(d4, a1, r);
            r = r1s[5 * kNT + m]; cfma(c5, a0, r); cfma(d5, a1, r);
        }
        T1a[0 * kNS + t] = c0; T1a[1 * kNS + t] = c1; T1a[2 * kNS + t] = c2;
        T1a[3 * kNS + t] = c3; T1a[4 * kNS + t] = c4; T1a[5 * kNS + t] = c5;
        T1b[0 * kNS + t] = d0; T1b[1 * kNS + t] = d1; T1b[2 * kNS + t] = d2;
        T1b[3 * kNS + t] = d3; T1b[4 * kNS + t] = d4; T1b[5 * kNS + t] = d5;
    }
    __syncthreads();
    for (int j = t; j < kM * kM * kNY; j += 256) {
        int l = j % kNY; int q = (j / kNY) % kM; int p = j / (kNY * kM);
        float2 a2 = make_float2(0.f, 0.f);
        float2 b2 = make_float2(0.f, 0.f);
        #pragma unroll
        for (int n = 0; n < kNX; ++n) {
            float2 r = r2s[q * kNX + n];
            cfma(a2, T1a[p * kNS + n * kNY + l], r);
            cfma(b2, T1b[p * kNS + n * kNY + l], r);
        }
        T2a[j] = a2;
        T2b[j] = b2;
    }
    __syncthreads();
    if (t < kMR) {
        int r = t % kM; int q = (t / kM) % kM; int p = t / (kM * kM);
        float2 t3a = make_float2(0.f, 0.f);
        float2 t3b = make_float2(0.f, 0.f);
        #pragma unroll
        for (int l = 0; l < kNY; ++l) {
            float2 rr = r3s[r * kNY + l];
            cfma(t3a, T2a[(p * kM + q) * kNY + l], rr);
            cfma(t3b, T2b[(p * kM + q) * kNY + l], rr);
        }
        float2 w = wrs[t];
        P[((size_t)(b0 * kC + k) * kC + i) * kMR + t] = cmul(w, t3a);
        P[((size_t)(b1 * kC + k) * kC + i) * kMR + t] = cmul(w, t3b);
    }
}

// K7b: or2[bk][t] = -sum_i P[(bk*16+i)*216+t]
__global__ __launch_bounds__(256) void k_or2red(
    const float2* __restrict__ P, float2* __restrict__ or2)
{
    int id = blockIdx.x * blockDim.x + threadIdx.x;
    if (id >= kB * kC * kMR) return;
    int t = id % kMR; int bk = id / kMR;
    float2 s = make_float2(0.f, 0.f);
    #pragma unroll
    for (int i = 0; i < kC; ++i) {
        float2 v = P[((size_t)bk * kC + i) * kMR + t];
        s.x += v.x; s.y += v.y;
    }
    or2[id] = make_float2(-s.x, -s.y);
}

// ---------------------------------------------------------------------------
// K8a: V[(b,k),(c,p),s] = sum_q ( sum_m or2[b,c,pqm] e3[c,k,m,y] ) e2[c,k,q,x]
// One block per (b,k,c) = 4096. s padded to kVS=256, tail zeroed.
// ---------------------------------------------------------------------------
__global__ __launch_bounds__(256) void k_x2v(
    const float2* __restrict__ or2,
    const float2* __restrict__ e2t, const float2* __restrict__ e3t,
    float2* __restrict__ Vg)
{
    int bid = blockIdx.x;
    int c = bid & 15; int rest = bid >> 4;
    int k = rest & 15; int b = rest >> 4;
    int ck = c * kC + k;
    __shared__ float2 o2s[kMR];
    __shared__ float2 e2s[kM * kNX];
    __shared__ float2 e3s[kM * kNY];
    __shared__ float2 Us[kM * kM * kNY];
    int t = threadIdx.x;
    if (t < kMR) o2s[t] = or2[(size_t)(b * kC + c) * kMR + t];
    if (t < kM * kNX) e2s[t] = e2t[(size_t)ck * (kM * kNX) + t];
    if (t < kM * kNY) e3s[t] = e3t[(size_t)ck * (kM * kNY) + t];
    __syncthreads();
    for (int j = t; j < kM * kM * kNY; j += 256) {
        int y = j % kNY, pq = j / kNY;
        float2 u = make_float2(0.f, 0.f);
        #pragma unroll
        for (int m = 0; m < kM; ++m) cfma(u, o2s[pq * kM + m], e3s[m * kNY + y]);
        Us[j] = u;
    }
    __syncthreads();
    size_t vbase = ((size_t)(b * kC + k) * (kC * kM) + c * kM) * kVS;
    for (int j = t; j < kM * kVS; j += 256) {
        int p = j >> 8, s = j & 255;
        float2 v = make_float2(0.f, 0.f);
        if (s < kNS) {
            int x = s / kNY, y = s % kNY;
            #pragma unroll
            for (int q = 0; q < kM; ++q)
                cfma(v, Us[(p * kM + q) * kNY + y], e2s[q * kNX + x]);
        }
        Vg[vbase + (size_t)p * kVS + s] = v;
    }
}

// ---------------------------------------------------------------------------
// K8b: out[b,k,z,s] = (1/7644) Re( sum_{cp} e1[c,k,p,z] V[(b,k),(c,p),s] )
// grid 768, zc-major (siblings same XCD). V staged chunk-wise into LDS
// (12 chunks x 8 rows, double-buffered): bulk linear copy Vs[j*256+t] =
// vpan[...], so each V element is read from global ONCE per block (was 4x)
// and HBM/L2 latency hides under the 256 FMAs per chunk.
// ---------------------------------------------------------------------------
__global__ __launch_bounds__(256) void k_x2gemm(
    const float2* __restrict__ Vg, const float2* __restrict__ e1t,
    float* __restrict__ outp)
{
    int bx = blockIdx.x;
    int bk = bx & 255, zc = bx >> 8;
    int k = bk & 15;
    int z0 = zc * 13;
    __shared__ float2 e1w[96 * 16];      // [(c,p)][zloc pad16], 12.3 KB
    __shared__ float2 Vs[2][8 * kVS];    // 2 x 16 KB chunk buffers
    int t = threadIdx.x;
    for (int j = t; j < 96 * 16; j += 256) {
        int row = j >> 4, zi = j & 15;
        int c = row / kM, p = row % kM;
        float2 e = make_float2(0.f, 0.f);
        if (zi < 13)
            e = e1t[((size_t)(c * kC + k) * kM + p) * kNT + z0 + zi];
        e1w[j] = e;
    }

    int sl = t & 63, zt = t >> 6;
    const float2* vpan = Vg + (size_t)bk * (kC * kM) * kVS;
    // preload chunk 0
    #pragma unroll
    for (int j = 0; j < 8; ++j) Vs[0][j * 256 + t] = vpan[j * 256 + t];
    __syncthreads();

    float acc[4][4];
    #pragma unroll
    for (int zi = 0; zi < 4; ++zi)
        #pragma unroll
        for (int j = 0; j < 4; ++j) acc[zi][j] = 0.f;

    for (int ch = 0; ch < 12; ++ch) {
        int cur = ch & 1;
        // prefetch next chunk into the other buffer (overlaps with FMA below)
        if (ch + 1 < 12) {
            const float2* src = vpan + (size_t)(ch + 1) * 8 * kVS;
            #pragma unroll
            for (int j = 0; j < 8; ++j) Vs[cur ^ 1][j * 256 + t] = src[j * 256 + t];
        }
        #pragma unroll
        for (int r = 0; r < 8; ++r) {
            int kk = ch * 8 + r;
            float2 vr[4];
            #pragma unroll
            for (int j = 0; j < 4; ++j) vr[j] = Vs[cur][r * 256 + sl + 64 * j];
            const int e1base = kk * 16 + zt;
            #pragma unroll
            for (int zi = 0; zi < 4; ++zi) {
                float2 e = e1w[e1base + 4 * zi];
                #pragma unroll
                for (int j = 0; j < 4; ++j)
                    acc[zi][j] = fmaf(vr[j].x, e.x, fmaf(-vr[j].y, e.y, acc[zi][j]));
            }
        }
        __syncthreads();
    }

    const float sc = 1.0f / 7644.0f;
    size_t base = (size_t)bk * kNF;
    #pragma unroll
    for (int zi = 0; zi < 4; ++zi) {
        int zloc = zt + 4 * zi;
        if (zloc < 13) {
            size_t zb = base + (size_t)(z0 + zloc) * kNS;
            #pragma unroll
            for (int j = 0; j < 4; ++j) {
                int s = sl + 64 * j;
                if (s < kNS) outp[zb + s] = acc[zi][j] * sc;
            }
        }
    }
}

// ---------------------------------------------------------------------------
extern "C" void kernel_launch(void* const* d_in, const int* in_sizes, int n_in,
                              void* d_out, int out_size, void* d_ws, size_t ws_size,
                              hipStream_t stream) {
    (void)in_sizes; (void)n_in; (void)out_size; (void)ws_size;
    const float* x      = (const float*)d_in[0];
    const float* wp1_re = (const float*)d_in[1];
    const float* wp1_im = (const float*)d_in[2];
    const float* wp2_re = (const float*)d_in[3];
    const float* wp2_im = (const float*)d_in[4];
    const float* wp3_re = (const float*)d_in[5];
    const float* wp3_im = (const float*)d_in[6];
    const float* wr_re  = (const float*)d_in[7];
    const float* wr_im  = (const float*)d_in[8];
    float* out = (float*)d_out;

    const size_t big = (size_t)kNIK * kNF;  // 1,956,864 complex (15.7 MB)
    float2* A   = (float2*)d_ws;            // dft scratch -> or1
    float2* Bb  = A + big;                  // alpha
    float2* Cc  = Bb + big;                 // H -> or2 partials -> t-ifft of or1
    float2* OR2 = Cc + big;                 // 55,296
    float2* r1t = OR2 + (size_t)kB * kC * kMR;
    float2* r2t = r1t + (size_t)kNIK * kM * kNT;
    float2* r3t = r2t + (size_t)kNIK * kM * kNX;
    float2* e1t = r3t + (size_t)kNIK * kM * kNY;
    float2* e2t = e1t + (size_t)kNIK * kM * kNT;
    float2* e3t = e2t + (size_t)kNIK * kM * kNX;
    float2* F39 = e3t + (size_t)kNIK * kM * kNY;
    float2* F14 = F39 + kNT * kNT;
    float2* Vg  = F14 + kNX * kNX;          // dedicated: 256*96*256 complex = 50 MB

    k_init<<<64, 256, 0, stream>>>(wp1_re, wp1_im, wp2_re, wp2_im, wp3_re, wp3_im,
                                   F39, F14, r1t, r2t, r3t, e1t, e2t, e3t);
    // forward DFT: x -> A (t-pass) -> Bb (fused xy). alpha lives in Bb.
    k_dft_t_real<<<dim3(kNIK, 3), 256, 0, stream>>>(x, F39, A);
    k_dft_xy<<<kNIK * kNT, 256, 0, stream>>>(A, F14, Bb);
    // transfer function H -> Cc; or1 -> A
    k_H<<<kNIK, 256, 0, stream>>>(wr_re, wr_im, r1t, r2t, r3t, Cc);
    k_or1<<<kNF / kFCH, 256, 0, stream>>>(Bb, Cc, A);
    // or2: partials into Cc (H dead), reduce -> OR2. Last readers of alpha (Bb).
    k_or2p<<<(kB / 2) * kC * kC, 256, 0, stream>>>(Bb, wr_re, wr_im, r1t, r2t, r3t, Cc);
    k_or2red<<<(kB * kC * kMR + 255) / 256, 256, 0, stream>>>(Cc, OR2);
    // x2: V (dedicated region) then GEMM directly into d_out (overwrite)
    k_x2v<<<kB * kC * kC, 256, 0, stream>>>(OR2, e2t, e3t, Vg);
    k_x2gemm<<<kB * kC * 3, 256, 0, stream>>>(Vg, e1t, out);
    // inverse FFT of or1 (in A): A -> Cc (t-pass; Cc partials dead) -> += out
    k_idft_t<<<dim3(kB * kC, 3), 256, 0, stream>>>(A, F39, Cc);
    k_idft_xy_final<<<kNIK * kNT, 256, 0, stream>>>(Cc, F14, out);
}

// Round 15
// 186.103 us; speedup vs baseline: 1.2255x; 1.0314x over previous
//
#include <hip/hip_runtime.h>

// Problem constants
constexpr int kB  = 16;    // batch
constexpr int kC  = 16;    // CI == CO
constexpr int kM  = 6;     // M1 == M2 == M3
constexpr int kNT = 39;
constexpr int kNX = 14;    // NXr
constexpr int kNY = 14;    // NYr
constexpr int kNS = kNX * kNY;       // 196
constexpr int kNF = kNT * kNS;       // 7644
constexpr int kNIK = kC * kC;        // 256
constexpr int kMR = kM * kM * kM;    // 216
constexpr int kFCH = 6;              // f-chunk for k_or1 (7644 = 6*1274)
constexpr int kVS = 256;             // padded s-stride for V

__device__ __forceinline__ float2 cmul(float2 a, float2 b) {
    return make_float2(a.x * b.x - a.y * b.y, a.x * b.y + a.y * b.x);
}
__device__ __forceinline__ void cfma(float2& c, float2 a, float2 b) {
    c.x = fmaf(a.x, b.x, fmaf(-a.y, b.y, c.x));
    c.y = fmaf(a.x, b.y, fmaf(a.y, b.x, c.y));
}

// ---------------------------------------------------------------------------
// K0: DFT matrices + pole-reciprocal tables r1/r2/r3 + exp tables e1/e2/e3
// ---------------------------------------------------------------------------
__global__ __launch_bounds__(256) void k_init(
    const float* __restrict__ wp1_re, const float* __restrict__ wp1_im,
    const float* __restrict__ wp2_re, const float* __restrict__ wp2_im,
    const float* __restrict__ wp3_re, const float* __restrict__ wp3_im,
    float2* __restrict__ F39, float2* __restrict__ F14,
    float2* __restrict__ r1t, float2* __restrict__ r2t, float2* __restrict__ r3t,
    float2* __restrict__ e1t, float2* __restrict__ e2t, float2* __restrict__ e3t)
{
    const float PI2 = 6.283185307179586f;
    int tid = blockIdx.x * blockDim.x + threadIdx.x;
    int nth = gridDim.x * blockDim.x;

    for (int idx = tid; idx < kNT * kNT; idx += nth) {
        int m = idx / kNT, t = idx % kNT;
        float ang = -PI2 * (float)((m * t) % kNT) / (float)kNT;
        float s, c; sincosf(ang, &s, &c);
        F39[idx] = make_float2(c, s);
    }
    for (int idx = tid; idx < kNX * kNX; idx += nth) {
        int a = idx / kNX, b = idx % kNX;
        float ang = -PI2 * (float)((a * b) % kNX) / (float)kNX;
        float s, c; sincosf(ang, &s, &c);
        F14[idx] = make_float2(c, s);
    }
    for (int idx = tid; idx < kNIK * kM * kNT; idx += nth) {
        int z = idx % kNT; int ikp = idx / kNT;
        float wre = wp1_re[ikp], wim = wp1_im[ikp];
        float f = (z < 20 ? (float)z : (float)(z - kNT)) / (float)kNT;
        float w = PI2 * f;
        float dr = -wre, di = w - wim;
        float inv = 1.0f / (dr * dr + di * di);
        r1t[idx] = make_float2(dr * inv, -di * inv);
        float tt = (float)z;
        float er = expf(wre * tt);
        float s, c; sincosf(wim * tt, &s, &c);
        e1t[idx] = make_float2(er * c, er * s);
    }
    for (int idx = tid; idx < kNIK * kM * kNX; idx += nth) {
        int n = idx % kNX; int ikq = idx / kNX;
        float f = (n <= 6 ? (float)n : (float)(n - kNX)) * 27.0f / 14.0f;
        float w = PI2 * f;
        float tx = (float)n * (1.0f / 27.0f);
        {
            float wre = wp2_re[ikq], wim = wp2_im[ikq];
            float dr = -wre, di = w - wim;
            float inv = 1.0f / (dr * dr + di * di);
            r2t[idx] = make_float2(dr * inv, -di * inv);
            float er = expf(wre * tx);
            float s, c; sincosf(wim * tx, &s, &c);
            e2t[idx] = make_float2(er * c, er * s);
        }
        {
            float wre = wp3_re[ikq], wim = wp3_im[ikq];
            float dr = -wre, di = w - wim;
            float inv = 1.0f / (dr * dr + di * di);
            r3t[idx] = make_float2(dr * inv, -di * inv);
            float er = expf(wre * tx);
            float s, c; sincosf(wim * tx, &s, &c);
            e3t[idx] = make_float2(er * c, er * s);
        }
    }
}

// ---------------------------------------------------------------------------
// Fused forward DFT (t then x then y). grid (bc, 3 mg). Thread owns s.
// Per m-row: t-DFT into LDS tile, then 14x14 two-pass DFT, write alpha.
// ---------------------------------------------------------------------------
__global__ __launch_bounds__(256) void k_dft_fwd(
    const float* __restrict__ x, const float2* __restrict__ F39,
    const float2* __restrict__ F14, float2* __restrict__ alpha)
{
    int bc = blockIdx.x, mg = blockIdx.y;
    __shared__ float2 Fs[13 * kNT];
    __shared__ float2 F14s[kNX * kNX];
    __shared__ float2 tile[kNS];
    __shared__ float2 tmp[kNS];
    int t = threadIdx.x;
    for (int j = t; j < 13 * kNT; j += 256)
        Fs[j] = F39[(mg * 13 + j / kNT) * kNT + (j % kNT)];
    for (int j = t; j < kNX * kNX; j += 256) F14s[j] = F14[j];

    float col[kNT];
    if (t < kNS) {
        const float* xp = x + (size_t)bc * kNF + t;
        #pragma unroll
        for (int tt = 0; tt < kNT; ++tt) col[tt] = xp[(size_t)tt * kNS];
    }
    __syncthreads();

    int n2 = t / kNY, l = t % kNY;
    for (int mi = 0; mi < 13; ++mi) {
        if (t < kNS) {
            float2 acc = make_float2(0.f, 0.f);
            #pragma unroll
            for (int tt = 0; tt < kNT; ++tt) {
                float2 f = Fs[mi * kNT + tt];
                acc.x = fmaf(f.x, col[tt], acc.x);
                acc.y = fmaf(f.y, col[tt], acc.y);
            }
            tile[t] = acc;
        }
        __syncthreads();
        if (t < kNS) {
            float2 acc = make_float2(0.f, 0.f);
            #pragma unroll
            for (int n = 0; n < kNX; ++n) cfma(acc, F14s[n2 * kNX + n], tile[n * kNY + l]);
            tmp[t] = acc;
        }
        __syncthreads();
        if (t < kNS) {
            float2 acc = make_float2(0.f, 0.f);
            #pragma unroll
            for (int ll = 0; ll < kNY; ++ll) cfma(acc, F14s[l * kNY + ll], tmp[n2 * kNY + ll]);
            alpha[((size_t)bc * kNT + mg * 13 + mi) * kNS + t] = acc;
        }
        __syncthreads();   // protect tile/tmp for next mi
    }
}

// ---------------------------------------------------------------------------
// Fused inverse DFT (conj): t then x then y, take real, scale, ADD into out.
// grid (bk, 3 zg). Runs AFTER out is fully written by k_x2red.
// ---------------------------------------------------------------------------
__global__ __launch_bounds__(256) void k_idft_fused(
    const float2* __restrict__ in, const float2* __restrict__ F39,
    const float2* __restrict__ F14, float* __restrict__ outp)
{
    int bk = blockIdx.x, zg = blockIdx.y;
    __shared__ float2 Fs[13 * kNT];
    __shared__ float2 F14s[kNX * kNX];
    __shared__ float2 tile[kNS];
    __shared__ float2 tmp[kNS];
    int t = threadIdx.x;
    for (int j = t; j < 13 * kNT; j += 256) {
        float2 f = F39[(zg * 13 + j / kNT) * kNT + (j % kNT)];
        f.y = -f.y;
        Fs[j] = f;
    }
    for (int j = t; j < kNX * kNX; j += 256) {
        float2 f = F14[j]; f.y = -f.y; F14s[j] = f;
    }

    float2 col[kNT];
    if (t < kNS) {
        const float2* ip = in + (size_t)bk * kNF + t;
        #pragma unroll
        for (int m = 0; m < kNT; ++m) col[m] = ip[(size_t)m * kNS];
    }
    __syncthreads();

    int n2 = t / kNY, l = t % kNY;
    const float sc = 1.0f / 7644.0f;
    for (int zi = 0; zi < 13; ++zi) {
        if (t < kNS) {
            float2 acc = make_float2(0.f, 0.f);
            #pragma unroll
            for (int m = 0; m < kNT; ++m) cfma(acc, Fs[zi * kNT + m], col[m]);
            tile[t] = acc;
        }
        __syncthreads();
        if (t < kNS) {
            float2 acc = make_float2(0.f, 0.f);
            #pragma unroll
            for (int n = 0; n < kNX; ++n) cfma(acc, F14s[n2 * kNX + n], tile[n * kNY + l]);
            tmp[t] = acc;
        }
        __syncthreads();
        if (t < kNS) {
            float2 acc = make_float2(0.f, 0.f);
            #pragma unroll
            for (int ll = 0; ll < kNY; ++ll) cfma(acc, F14s[l * kNY + ll], tmp[n2 * kNY + ll]);
            outp[((size_t)bk * kNT + zg * 13 + zi) * kNS + t] += acc.x * sc;
        }
        __syncthreads();
    }
}

// ---------------------------------------------------------------------------
// K4: H[i,k,m,n,l] = sum_{p,q,r} wr[i,k,p,q,r] r1[m] r2[n] r3[l]; block per (i,k)
// ---------------------------------------------------------------------------
__global__ __launch_bounds__(256) void k_H(
    const float* __restrict__ wr_re, const float* __restrict__ wr_im,
    const float2* __restrict__ r1t, const float2* __restrict__ r2t,
    const float2* __restrict__ r3t, float2* __restrict__ H)
{
    int ik = blockIdx.x;
    __shared__ float2 wrs[kMR];
    __shared__ float2 r1s[kM * kNT];
    __shared__ float2 r2s[kM * kNX];
    __shared__ float2 r3s[kM * kNY];
    __shared__ float2 As[kM * kM * kNY];
    __shared__ float2 Ss[kM * kNS];
    int t = threadIdx.x;
    for (int j = t; j < kMR; j += 256)
        wrs[j] = make_float2(wr_re[ik * kMR + j], wr_im[ik * kMR + j]);
    for (int j = t; j < kM * kNT; j += 256) r1s[j] = r1t[(size_t)ik * kM * kNT + j];
    for (int j = t; j < kM * kNX; j += 256) r2s[j] = r2t[(size_t)ik * kM * kNX + j];
    for (int j = t; j < kM * kNY; j += 256) r3s[j] = r3t[(size_t)ik * kM * kNY + j];
    __syncthreads();
    for (int j = t; j < kM * kM * kNY; j += 256) {
        int l = j % kNY; int pq = j / kNY;
        float2 acc = make_float2(0.f, 0.f);
        #pragma unroll
        for (int r = 0; r < kM; ++r) cfma(acc, wrs[pq * kM + r], r3s[r * kNY + l]);
        As[j] = acc;
    }
    __syncthreads();
    for (int j = t; j < kM * kNS; j += 256) {
        int l = j % kNY; int n = (j / kNY) % kNX; int p = j / kNS;
        float2 acc = make_float2(0.f, 0.f);
        #pragma unroll
        for (int q = 0; q < kM; ++q) cfma(acc, r2s[q * kNX + n], As[(p * kM + q) * kNY + l]);
        Ss[j] = acc;
    }
    __syncthreads();
    for (int j = t; j < kNF; j += 256) {
        int m = j / kNS; int nl = j % kNS;
        float2 acc = make_float2(0.f, 0.f);
        #pragma unroll
        for (int p = 0; p < kM; ++p) cfma(acc, r1s[p * kNT + m], Ss[p * kNS + nl]);
        H[(size_t)ik * kNF + j] = acc;
    }
}

// ---------------------------------------------------------------------------
// K5: or1[b,k,f] = sum_i alpha[b,i,f] * H[i,k,f]
// ---------------------------------------------------------------------------
__global__ __launch_bounds__(256) void k_or1(
    const float2* __restrict__ alpha, const float2* __restrict__ H, float2* __restrict__ out)
{
    int f0 = blockIdx.x * kFCH;
    __shared__ float2 As[256 * 7 + 16];
    __shared__ float2 Hs[256 * 7 + 16];
    int t = threadIdx.x;
    {
        const float2* ap = alpha + (size_t)t * kNF + f0;
        const float2* hp = H + (size_t)t * kNF + f0;
        int base = t * 7 + (t >> 4);
        #pragma unroll
        for (int j = 0; j < kFCH; ++j) {
            As[base + j] = ap[j];
            Hs[base + j] = hp[j];
        }
    }
    __syncthreads();
    int b = t >> 4, k = t & 15;
    float2 acc[kFCH];
    #pragma unroll
    for (int j = 0; j < kFCH; ++j) acc[j] = make_float2(0.f, 0.f);
    #pragma unroll
    for (int i = 0; i < kC; ++i) {
        int ai = (b * 16 + i) * 7 + b;
        int hi = (i * 16 + k) * 7 + i;
        #pragma unroll
        for (int j = 0; j < kFCH; ++j) cfma(acc[j], As[ai + j], Hs[hi + j]);
    }
    float2* op = out + (size_t)t * kNF + f0;
    #pragma unroll
    for (int j = 0; j < kFCH; ++j) op[j] = acc[j];
}

// ---------------------------------------------------------------------------
// K7a: partial or2 per (b-pair,k,i).
// ---------------------------------------------------------------------------
__global__ __launch_bounds__(256) void k_or2p(
    const float2* __restrict__ alpha,
    const float* __restrict__ wr_re, const float* __restrict__ wr_im,
    const float2* __restrict__ r1t, const float2* __restrict__ r2t,
    const float2* __restrict__ r3t, float2* __restrict__ P)
{
    int blk = blockIdx.x;            // (pb*16 + k)*16 + i
    int i = blk % kC; int rest = blk / kC;
    int k = rest % kC; int pb = rest / kC;
    int b0 = 2 * pb, b1 = 2 * pb + 1;
    int ik = i * kC + k;
    __shared__ float2 r1s[kM * kNT];
    __shared__ float2 r2s[kM * kNX];
    __shared__ float2 r3s[kM * kNY];
    __shared__ float2 wrs[kMR];
    __shared__ float2 T1a[kM * kNS];
    __shared__ float2 T1b[kM * kNS];
    __shared__ float2 T2a[kM * kM * kNY];
    __shared__ float2 T2b[kM * kM * kNY];
    int t = threadIdx.x;
    for (int j = t; j < kM * kNT; j += 256) r1s[j] = r1t[(size_t)ik * kM * kNT + j];
    for (int j = t; j < kM * kNX; j += 256) r2s[j] = r2t[(size_t)ik * kM * kNX + j];
    for (int j = t; j < kM * kNY; j += 256) r3s[j] = r3t[(size_t)ik * kM * kNY + j];
    for (int j = t; j < kMR; j += 256)
        wrs[j] = make_float2(wr_re[ik * kMR + j], wr_im[ik * kMR + j]);
    __syncthreads();
    if (t < kNS) {
        float2 c0 = make_float2(0.f, 0.f), c1 = c0, c2 = c0, c3 = c0, c4 = c0, c5 = c0;
        float2 d0 = c0, d1 = c0, d2 = c0, d3 = c0, d4 = c0, d5 = c0;
        const float2* ap0 = alpha + (size_t)(b0 * kC + i) * kNF + t;
        const float2* ap1 = alpha + (size_t)(b1 * kC + i) * kNF + t;
        for (int m = 0; m < kNT; ++m) {
            float2 a0 = ap0[(size_t)m * kNS];
            float2 a1 = ap1[(size_t)m * kNS];
            float2 r;
            r = r1s[0 * kNT + m]; cfma(c0, a0, r); cfma(d0, a1, r);
            r = r1s[1 * kNT + m]; cfma(c1, a0, r); cfma(d1, a1, r);
            r = r1s[2 * kNT + m]; cfma(c2, a0, r); cfma(d2, a1, r);
            r = r1s[3 * kNT + m]; cfma(c3, a0, r); cfma(d3, a1, r);
            r = r1s[4 * kNT + m]; cfma(c4, a0, r); cfma(d4, a1, r);
            r = r1s[5 * kNT + m]; cfma(c5, a0, r); cfma(d5, a1, r);
        }
        T1a[0 * kNS + t] = c0; T1a[1 * kNS + t] = c1; T1a[2 * kNS + t] = c2;
        T1a[3 * kNS + t] = c3; T1a[4 * kNS + t] = c4; T1a[5 * kNS + t] = c5;
        T1b[0 * kNS + t] = d0; T1b[1 * kNS + t] = d1; T1b[2 * kNS + t] = d2;
        T1b[3 * kNS + t] = d3; T1b[4 * kNS + t] = d4; T1b[5 * kNS + t] = d5;
    }
    __syncthreads();
    for (int j = t; j < kM * kM * kNY; j += 256) {
        int l = j % kNY; int q = (j / kNY) % kM; int p = j / (kNY * kM);
        float2 a2 = make_float2(0.f, 0.f);
        float2 b2 = make_float2(0.f, 0.f);
        #pragma unroll
        for (int n = 0; n < kNX; ++n) {
            float2 r = r2s[q * kNX + n];
            cfma(a2, T1a[p * kNS + n * kNY + l], r);
            cfma(b2, T1b[p * kNS + n * kNY + l], r);
        }
        T2a[j] = a2;
        T2b[j] = b2;
    }
    __syncthreads();
    if (t < kMR) {
        int r = t % kM; int q = (t / kM) % kM; int p = t / (kM * kM);
        float2 t3a = make_float2(0.f, 0.f);
        float2 t3b = make_float2(0.f, 0.f);
        #pragma unroll
        for (int l = 0; l < kNY; ++l) {
            float2 rr = r3s[r * kNY + l];
            cfma(t3a, T2a[(p * kM + q) * kNY + l], rr);
            cfma(t3b, T2b[(p * kM + q) * kNY + l], rr);
        }
        float2 w = wrs[t];
        P[((size_t)(b0 * kC + k) * kC + i) * kMR + t] = cmul(w, t3a);
        P[((size_t)(b1 * kC + k) * kC + i) * kMR + t] = cmul(w, t3b);
    }
}

// K7b: or2[bk][t] = -sum_i P[(bk*16+i)*216+t]
__global__ __launch_bounds__(256) void k_or2red(
    const float2* __restrict__ P, float2* __restrict__ or2)
{
    int id = blockIdx.x * blockDim.x + threadIdx.x;
    if (id >= kB * kC * kMR) return;
    int t = id % kMR; int bk = id / kMR;
    float2 s = make_float2(0.f, 0.f);
    #pragma unroll
    for (int i = 0; i < kC; ++i) {
        float2 v = P[((size_t)bk * kC + i) * kMR + t];
        s.x += v.x; s.y += v.y;
    }
    or2[id] = make_float2(-s.x, -s.y);
}

// ---------------------------------------------------------------------------
// K8a: V[(b,k),(c,p),s]; one block per (b,k,c) = 4096. s padded to kVS=256.
// ---------------------------------------------------------------------------
__global__ __launch_bounds__(256) void k_x2v(
    const float2* __restrict__ or2,
    const float2* __restrict__ e2t, const float2* __restrict__ e3t,
    float2* __restrict__ Vg)
{
    int bid = blockIdx.x;
    int c = bid & 15; int rest = bid >> 4;
    int k = rest & 15; int b = rest >> 4;
    int ck = c * kC + k;
    __shared__ float2 o2s[kMR];
    __shared__ float2 e2s[kM * kNX];
    __shared__ float2 e3s[kM * kNY];
    __shared__ float2 Us[kM * kM * kNY];
    int t = threadIdx.x;
    if (t < kMR) o2s[t] = or2[(size_t)(b * kC + c) * kMR + t];
    if (t < kM * kNX) e2s[t] = e2t[(size_t)ck * (kM * kNX) + t];
    if (t < kM * kNY) e3s[t] = e3t[(size_t)ck * (kM * kNY) + t];
    __syncthreads();
    for (int j = t; j < kM * kM * kNY; j += 256) {
        int y = j % kNY, pq = j / kNY;
        float2 u = make_float2(0.f, 0.f);
        #pragma unroll
        for (int m = 0; m < kM; ++m) cfma(u, o2s[pq * kM + m], e3s[m * kNY + y]);
        Us[j] = u;
    }
    __syncthreads();
    size_t vbase = ((size_t)(b * kC + k) * (kC * kM) + c * kM) * kVS;
    for (int j = t; j < kM * kVS; j += 256) {
        int p = j >> 8, s = j & 255;
        float2 v = make_float2(0.f, 0.f);
        if (s < kNS) {
            int x = s / kNY, y = s % kNY;
            #pragma unroll
            for (int q = 0; q < kM; ++q)
                cfma(v, Us[(p * kM + q) * kNY + y], e2s[q * kNX + x]);
        }
        Vg[vbase + (size_t)p * kVS + s] = v;
    }
}

// ---------------------------------------------------------------------------
// K8b: partial x2 GEMM, K split in 2 halves of 48. grid 1536 =
// (kh*3+zc)*256 + bk  (all 6 siblings of a bk same XCD). LDS: e1w 6KB +
// Vs 2x8KB = 22KB -> occupancy not LDS-capped (6 blocks/CU from grid).
// Writes float partials P2[kh][bk][z0+zloc][s] (no scale).
// ---------------------------------------------------------------------------
__global__ __launch_bounds__(256) void k_x2gemm(
    const float2* __restrict__ Vg, const float2* __restrict__ e1t,
    float* __restrict__ P2)
{
    int bx = blockIdx.x;
    int bk = bx & 255;
    int zckh = bx >> 8;            // 0..5 = kh*3 + zc
    int kh = zckh / 3, zc = zckh % 3;
    int k = bk & 15;
    int z0 = zc * 13;
    __shared__ float2 e1w[48 * 16];      // rows kh*48..kh*48+47, zloc pad16
    __shared__ float2 Vs[2][4 * kVS];    // 2 x 8 KB chunk buffers (4 rows)
    int t = threadIdx.x;
    for (int j = t; j < 48 * 16; j += 256) {
        int row = j >> 4, zi = j & 15;
        int cp = kh * 48 + row;
        int c = cp / kM, p = cp % kM;
        float2 e = make_float2(0.f, 0.f);
        if (zi < 13)
            e = e1t[((size_t)(c * kC + k) * kM + p) * kNT + z0 + zi];
        e1w[j] = e;
    }

    int sl = t & 63, zt = t >> 6;
    const float2* vpan = Vg + (size_t)bk * (kC * kM) * kVS + (size_t)kh * 48 * kVS;
    // preload chunk 0 (4 rows; thread copies 4 elements)
    #pragma unroll
    for (int j = 0; j < 4; ++j) Vs[0][j * 256 + t] = vpan[j * 256 + t];
    __syncthreads();

    float acc[4][4];
    #pragma unroll
    for (int zi = 0; zi < 4; ++zi)
        #pragma unroll
        for (int j = 0; j < 4; ++j) acc[zi][j] = 0.f;

    for (int ch = 0; ch < 12; ++ch) {
        int cur = ch & 1;
        if (ch + 1 < 12) {
            const float2* src = vpan + (size_t)(ch + 1) * 4 * kVS;
            #pragma unroll
            for (int j = 0; j < 4; ++j) Vs[cur ^ 1][j * 256 + t] = src[j * 256 + t];
        }
        #pragma unroll
        for (int r = 0; r < 4; ++r) {
            int row = ch * 4 + r;
            float2 vr[4];
            #pragma unroll
            for (int j = 0; j < 4; ++j) vr[j] = Vs[cur][r * 256 + sl + 64 * j];
            const int e1base = row * 16 + zt;
            #pragma unroll
            for (int zi = 0; zi < 4; ++zi) {
                float2 e = e1w[e1base + 4 * zi];
                #pragma unroll
                for (int j = 0; j < 4; ++j)
                    acc[zi][j] = fmaf(vr[j].x, e.x, fmaf(-vr[j].y, e.y, acc[zi][j]));
            }
        }
        __syncthreads();
    }

    size_t base = ((size_t)kh * kNIK + bk) * kNF;
    #pragma unroll
    for (int zi = 0; zi < 4; ++zi) {
        int zloc = zt + 4 * zi;
        if (zloc < 13) {
            size_t zb = base + (size_t)(z0 + zloc) * kNS;
            #pragma unroll
            for (int j = 0; j < 4; ++j) {
                int s = sl + 64 * j;
                if (s < kNS) P2[zb + s] = acc[zi][j];
            }
        }
    }
}

// K8c: out[bk*kNF+f] = (P2[0][bk][f] + P2[1][bk][f]) / 7644  (overwrite)
__global__ __launch_bounds__(256) void k_x2red(
    const float* __restrict__ P2, float* __restrict__ outp)
{
    int id = blockIdx.x * blockDim.x + threadIdx.x;
    if (id >= kNIK * kNF) return;
    const float sc = 1.0f / 7644.0f;
    outp[id] = (P2[id] + P2[(size_t)kNIK * kNF + id]) * sc;
}

// ---------------------------------------------------------------------------
extern "C" void kernel_launch(void* const* d_in, const int* in_sizes, int n_in,
                              void* d_out, int out_size, void* d_ws, size_t ws_size,
                              hipStream_t stream) {
    (void)in_sizes; (void)n_in; (void)out_size; (void)ws_size;
    const float* x      = (const float*)d_in[0];
    const float* wp1_re = (const float*)d_in[1];
    const float* wp1_im = (const float*)d_in[2];
    const float* wp2_re = (const float*)d_in[3];
    const float* wp2_im = (const float*)d_in[4];
    const float* wp3_re = (const float*)d_in[5];
    const float* wp3_im = (const float*)d_in[6];
    const float* wr_re  = (const float*)d_in[7];
    const float* wr_im  = (const float*)d_in[8];
    float* out = (float*)d_out;

    const size_t big = (size_t)kNIK * kNF;  // 1,956,864 complex (15.7 MB)
    float2* A   = (float2*)d_ws;            // or1
    float2* Bb  = A + big;                  // alpha
    float2* Cc  = Bb + big;                 // H -> or2 partials -> x2 float partials
    float2* OR2 = Cc + big;                 // 55,296
    float2* r1t = OR2 + (size_t)kB * kC * kMR;
    float2* r2t = r1t + (size_t)kNIK * kM * kNT;
    float2* r3t = r2t + (size_t)kNIK * kM * kNX;
    float2* e1t = r3t + (size_t)kNIK * kM * kNY;
    float2* e2t = e1t + (size_t)kNIK * kM * kNT;
    float2* e3t = e2t + (size_t)kNIK * kM * kNX;
    float2* F39 = e3t + (size_t)kNIK * kM * kNY;
    float2* F14 = F39 + kNT * kNT;
    float2* Vg  = F14 + kNX * kNX;          // dedicated: 256*96*256 complex = 50 MB

    k_init<<<64, 256, 0, stream>>>(wp1_re, wp1_im, wp2_re, wp2_im, wp3_re, wp3_im,
                                   F39, F14, r1t, r2t, r3t, e1t, e2t, e3t);
    // fused forward DFT: x -> Bb (alpha)
    k_dft_fwd<<<dim3(kNIK, 3), 256, 0, stream>>>(x, F39, F14, Bb);
    // transfer function H -> Cc; or1 -> A
    k_H<<<kNIK, 256, 0, stream>>>(wr_re, wr_im, r1t, r2t, r3t, Cc);
    k_or1<<<kNF / kFCH, 256, 0, stream>>>(Bb, Cc, A);
    // or2: partials into Cc (H dead), reduce -> OR2
    k_or2p<<<(kB / 2) * kC * kC, 256, 0, stream>>>(Bb, wr_re, wr_im, r1t, r2t, r3t, Cc);
    k_or2red<<<(kB * kC * kMR + 255) / 256, 256, 0, stream>>>(Cc, OR2);
    // x2: V -> Vg; K-split GEMM partials -> Cc (or2 partials dead); reduce -> out
    k_x2v<<<kB * kC * kC, 256, 0, stream>>>(OR2, e2t, e3t, Vg);
    k_x2gemm<<<kB * kC * 6, 256, 0, stream>>>(Vg, e1t, (float*)Cc);
    k_x2red<<<(int)((big + 255) / 256), 256, 0, stream>>>((const float*)Cc, out);
    // fused inverse DFT of or1 (A) + add into out
    k_idft_fused<<<dim3(kB * kC, 3), 256, 0, stream>>>(A, F39, F14, out);
}

// Round 17
// 183.640 us; speedup vs baseline: 1.2419x; 1.0134x over previous
//
#include <hip/hip_runtime.h>

// Problem constants
constexpr int kB  = 16;    // batch
constexpr int kC  = 16;    // CI == CO
constexpr int kM  = 6;     // M1 == M2 == M3
constexpr int kNT = 39;
constexpr int kNX = 14;    // NXr
constexpr int kNY = 14;    // NYr
constexpr int kNS = kNX * kNY;       // 196
constexpr int kNF = kNT * kNS;       // 7644
constexpr int kNIK = kC * kC;        // 256
constexpr int kMR = kM * kM * kM;    // 216
constexpr int kFCH = 6;              // f-chunk for k_or1 (7644 = 6*1274)
constexpr int kVS = 256;             // padded s-stride for V

__device__ __forceinline__ float2 cmul(float2 a, float2 b) {
    return make_float2(a.x * b.x - a.y * b.y, a.x * b.y + a.y * b.x);
}
__device__ __forceinline__ void cfma(float2& c, float2 a, float2 b) {
    c.x = fmaf(a.x, b.x, fmaf(-a.y, b.y, c.x));
    c.y = fmaf(a.x, b.y, fmaf(a.y, b.x, c.y));
}

// ---------------------------------------------------------------------------
// K0: DFT matrices + pole-reciprocal tables r1/r2/r3 + exp tables e1/e2/e3
// ---------------------------------------------------------------------------
__global__ __launch_bounds__(256) void k_init(
    const float* __restrict__ wp1_re, const float* __restrict__ wp1_im,
    const float* __restrict__ wp2_re, const float* __restrict__ wp2_im,
    const float* __restrict__ wp3_re, const float* __restrict__ wp3_im,
    float2* __restrict__ F39, float2* __restrict__ F14,
    float2* __restrict__ r1t, float2* __restrict__ r2t, float2* __restrict__ r3t,
    float2* __restrict__ e1t, float2* __restrict__ e2t, float2* __restrict__ e3t)
{
    const float PI2 = 6.283185307179586f;
    int tid = blockIdx.x * blockDim.x + threadIdx.x;
    int nth = gridDim.x * blockDim.x;

    for (int idx = tid; idx < kNT * kNT; idx += nth) {
        int m = idx / kNT, t = idx % kNT;
        float ang = -PI2 * (float)((m * t) % kNT) / (float)kNT;
        float s, c; sincosf(ang, &s, &c);
        F39[idx] = make_float2(c, s);
    }
    for (int idx = tid; idx < kNX * kNX; idx += nth) {
        int a = idx / kNX, b = idx % kNX;
        float ang = -PI2 * (float)((a * b) % kNX) / (float)kNX;
        float s, c; sincosf(ang, &s, &c);
        F14[idx] = make_float2(c, s);
    }
    for (int idx = tid; idx < kNIK * kM * kNT; idx += nth) {
        int z = idx % kNT; int ikp = idx / kNT;
        float wre = wp1_re[ikp], wim = wp1_im[ikp];
        float f = (z < 20 ? (float)z : (float)(z - kNT)) / (float)kNT;
        float w = PI2 * f;
        float dr = -wre, di = w - wim;
        float inv = 1.0f / (dr * dr + di * di);
        r1t[idx] = make_float2(dr * inv, -di * inv);
        float tt = (float)z;
        float er = expf(wre * tt);
        float s, c; sincosf(wim * tt, &s, &c);
        e1t[idx] = make_float2(er * c, er * s);
    }
    for (int idx = tid; idx < kNIK * kM * kNX; idx += nth) {
        int n = idx % kNX; int ikq = idx / kNX;
        float f = (n <= 6 ? (float)n : (float)(n - kNX)) * 27.0f / 14.0f;
        float w = PI2 * f;
        float tx = (float)n * (1.0f / 27.0f);
        {
            float wre = wp2_re[ikq], wim = wp2_im[ikq];
            float dr = -wre, di = w - wim;
            float inv = 1.0f / (dr * dr + di * di);
            r2t[idx] = make_float2(dr * inv, -di * inv);
            float er = expf(wre * tx);
            float s, c; sincosf(wim * tx, &s, &c);
            e2t[idx] = make_float2(er * c, er * s);
        }
        {
            float wre = wp3_re[ikq], wim = wp3_im[ikq];
            float dr = -wre, di = w - wim;
            float inv = 1.0f / (dr * dr + di * di);
            r3t[idx] = make_float2(dr * inv, -di * inv);
            float er = expf(wre * tx);
            float s, c; sincosf(wim * tx, &s, &c);
            e3t[idx] = make_float2(er * c, er * s);
        }
    }
}

// ---------------------------------------------------------------------------
// Fused forward DFT (t then x then y). grid (bc, 3 mg). Thread owns s.
// ---------------------------------------------------------------------------
__global__ __launch_bounds__(256) void k_dft_fwd(
    const float* __restrict__ x, const float2* __restrict__ F39,
    const float2* __restrict__ F14, float2* __restrict__ alpha)
{
    int bc = blockIdx.x, mg = blockIdx.y;
    __shared__ float2 Fs[13 * kNT];
    __shared__ float2 F14s[kNX * kNX];
    __shared__ float2 tile[kNS];
    __shared__ float2 tmp[kNS];
    int t = threadIdx.x;
    for (int j = t; j < 13 * kNT; j += 256)
        Fs[j] = F39[(mg * 13 + j / kNT) * kNT + (j % kNT)];
    for (int j = t; j < kNX * kNX; j += 256) F14s[j] = F14[j];

    float col[kNT];
    if (t < kNS) {
        const float* xp = x + (size_t)bc * kNF + t;
        #pragma unroll
        for (int tt = 0; tt < kNT; ++tt) col[tt] = xp[(size_t)tt * kNS];
    }
    __syncthreads();

    int n2 = t / kNY, l = t % kNY;
    for (int mi = 0; mi < 13; ++mi) {
        if (t < kNS) {
            float2 acc = make_float2(0.f, 0.f);
            #pragma unroll
            for (int tt = 0; tt < kNT; ++tt) {
                float2 f = Fs[mi * kNT + tt];
                acc.x = fmaf(f.x, col[tt], acc.x);
                acc.y = fmaf(f.y, col[tt], acc.y);
            }
            tile[t] = acc;
        }
        __syncthreads();
        if (t < kNS) {
            float2 acc = make_float2(0.f, 0.f);
            #pragma unroll
            for (int n = 0; n < kNX; ++n) cfma(acc, F14s[n2 * kNX + n], tile[n * kNY + l]);
            tmp[t] = acc;
        }
        __syncthreads();
        if (t < kNS) {
            float2 acc = make_float2(0.f, 0.f);
            #pragma unroll
            for (int ll = 0; ll < kNY; ++ll) cfma(acc, F14s[l * kNY + ll], tmp[n2 * kNY + ll]);
            alpha[((size_t)bc * kNT + mg * 13 + mi) * kNS + t] = acc;
        }
        __syncthreads();   // protect tile/tmp for next mi
    }
}

// ---------------------------------------------------------------------------
// Fused inverse DFT + x2 combine. grid (bk, 3 zg). OVERWRITES out:
// out = (ifft(or1).x + P2[0] + P2[1]) / 7644
// ---------------------------------------------------------------------------
__global__ __launch_bounds__(256) void k_idft_fused(
    const float2* __restrict__ in, const float2* __restrict__ F39,
    const float2* __restrict__ F14, const float* __restrict__ P2,
    float* __restrict__ outp)
{
    int bk = blockIdx.x, zg = blockIdx.y;
    __shared__ float2 Fs[13 * kNT];
    __shared__ float2 F14s[kNX * kNX];
    __shared__ float2 tile[kNS];
    __shared__ float2 tmp[kNS];
    int t = threadIdx.x;
    for (int j = t; j < 13 * kNT; j += 256) {
        float2 f = F39[(zg * 13 + j / kNT) * kNT + (j % kNT)];
        f.y = -f.y;
        Fs[j] = f;
    }
    for (int j = t; j < kNX * kNX; j += 256) {
        float2 f = F14[j]; f.y = -f.y; F14s[j] = f;
    }

    float2 col[kNT];
    if (t < kNS) {
        const float2* ip = in + (size_t)bk * kNF + t;
        #pragma unroll
        for (int m = 0; m < kNT; ++m) col[m] = ip[(size_t)m * kNS];
    }
    __syncthreads();

    int n2 = t / kNY, l = t % kNY;
    const float sc = 1.0f / 7644.0f;
    for (int zi = 0; zi < 13; ++zi) {
        if (t < kNS) {
            float2 acc = make_float2(0.f, 0.f);
            #pragma unroll
            for (int m = 0; m < kNT; ++m) cfma(acc, Fs[zi * kNT + m], col[m]);
            tile[t] = acc;
        }
        __syncthreads();
        if (t < kNS) {
            float2 acc = make_float2(0.f, 0.f);
            #pragma unroll
            for (int n = 0; n < kNX; ++n) cfma(acc, F14s[n2 * kNX + n], tile[n * kNY + l]);
            tmp[t] = acc;
        }
        __syncthreads();
        if (t < kNS) {
            float2 acc = make_float2(0.f, 0.f);
            #pragma unroll
            for (int ll = 0; ll < kNY; ++ll) cfma(acc, F14s[l * kNY + ll], tmp[n2 * kNY + ll]);
            size_t idx = ((size_t)bk * kNT + zg * 13 + zi) * kNS + t;
            outp[idx] = (acc.x + P2[idx] + P2[(size_t)kNIK * kNF + idx]) * sc;
        }
        __syncthreads();
    }
}

// ---------------------------------------------------------------------------
// K4: H[i,k,m,n,l] = sum_{p,q,r} wr[i,k,p,q,r] r1[m] r2[n] r3[l]; block per (i,k)
// ---------------------------------------------------------------------------
__global__ __launch_bounds__(256) void k_H(
    const float* __restrict__ wr_re, const float* __restrict__ wr_im,
    const float2* __restrict__ r1t, const float2* __restrict__ r2t,
    const float2* __restrict__ r3t, float2* __restrict__ H)
{
    int ik = blockIdx.x;
    __shared__ float2 wrs[kMR];
    __shared__ float2 r1s[kM * kNT];
    __shared__ float2 r2s[kM * kNX];
    __shared__ float2 r3s[kM * kNY];
    __shared__ float2 As[kM * kM * kNY];
    __shared__ float2 Ss[kM * kNS];
    int t = threadIdx.x;
    for (int j = t; j < kMR; j += 256)
        wrs[j] = make_float2(wr_re[ik * kMR + j], wr_im[ik * kMR + j]);
    for (int j = t; j < kM * kNT; j += 256) r1s[j] = r1t[(size_t)ik * kM * kNT + j];
    for (int j = t; j < kM * kNX; j += 256) r2s[j] = r2t[(size_t)ik * kM * kNX + j];
    for (int j = t; j < kM * kNY; j += 256) r3s[j] = r3t[(size_t)ik * kM * kNY + j];
    __syncthreads();
    for (int j = t; j < kM * kM * kNY; j += 256) {
        int l = j % kNY; int pq = j / kNY;
        float2 acc = make_float2(0.f, 0.f);
        #pragma unroll
        for (int r = 0; r < kM; ++r) cfma(acc, wrs[pq * kM + r], r3s[r * kNY + l]);
        As[j] = acc;
    }
    __syncthreads();
    for (int j = t; j < kM * kNS; j += 256) {
        int l = j % kNY; int n = (j / kNY) % kNX; int p = j / kNS;
        float2 acc = make_float2(0.f, 0.f);
        #pragma unroll
        for (int q = 0; q < kM; ++q) cfma(acc, r2s[q * kNX + n], As[(p * kM + q) * kNY + l]);
        Ss[j] = acc;
    }
    __syncthreads();
    for (int j = t; j < kNF; j += 256) {
        int m = j / kNS; int nl = j % kNS;
        float2 acc = make_float2(0.f, 0.f);
        #pragma unroll
        for (int p = 0; p < kM; ++p) cfma(acc, r1s[p * kNT + m], Ss[p * kNS + nl]);
        H[(size_t)ik * kNF + j] = acc;
    }
}

// ---------------------------------------------------------------------------
// K5: or1[b,k,f] = sum_i alpha[b,i,f] * H[i,k,f]
// ---------------------------------------------------------------------------
__global__ __launch_bounds__(256) void k_or1(
    const float2* __restrict__ alpha, const float2* __restrict__ H, float2* __restrict__ out)
{
    int f0 = blockIdx.x * kFCH;
    __shared__ float2 As[256 * 7 + 16];
    __shared__ float2 Hs[256 * 7 + 16];
    int t = threadIdx.x;
    {
        const float2* ap = alpha + (size_t)t * kNF + f0;
        const float2* hp = H + (size_t)t * kNF + f0;
        int base = t * 7 + (t >> 4);
        #pragma unroll
        for (int j = 0; j < kFCH; ++j) {
            As[base + j] = ap[j];
            Hs[base + j] = hp[j];
        }
    }
    __syncthreads();
    int b = t >> 4, k = t & 15;
    float2 acc[kFCH];
    #pragma unroll
    for (int j = 0; j < kFCH; ++j) acc[j] = make_float2(0.f, 0.f);
    #pragma unroll
    for (int i = 0; i < kC; ++i) {
        int ai = (b * 16 + i) * 7 + b;
        int hi = (i * 16 + k) * 7 + i;
        #pragma unroll
        for (int j = 0; j < kFCH; ++j) cfma(acc[j], As[ai + j], Hs[hi + j]);
    }
    float2* op = out + (size_t)t * kNF + f0;
    #pragma unroll
    for (int j = 0; j < kFCH; ++j) op[j] = acc[j];
}

// ---------------------------------------------------------------------------
// K7a: partial or2 per (b-pair,k,i).
// ---------------------------------------------------------------------------
__global__ __launch_bounds__(256) void k_or2p(
    const float2* __restrict__ alpha,
    const float* __restrict__ wr_re, const float* __restrict__ wr_im,
    const float2* __restrict__ r1t, const float2* __restrict__ r2t,
    const float2* __restrict__ r3t, float2* __restrict__ P)
{
    int blk = blockIdx.x;            // (pb*16 + k)*16 + i
    int i = blk % kC; int rest = blk / kC;
    int k = rest % kC; int pb = rest / kC;
    int b0 = 2 * pb, b1 = 2 * pb + 1;
    int ik = i * kC + k;
    __shared__ float2 r1s[kM * kNT];
    __shared__ float2 r2s[kM * kNX];
    __shared__ float2 r3s[kM * kNY];
    __shared__ float2 wrs[kMR];
    __shared__ float2 T1a[kM * kNS];
    __shared__ float2 T1b[kM * kNS];
    __shared__ float2 T2a[kM * kM * kNY];
    __shared__ float2 T2b[kM * kM * kNY];
    int t = threadIdx.x;
    for (int j = t; j < kM * kNT; j += 256) r1s[j] = r1t[(size_t)ik * kM * kNT + j];
    for (int j = t; j < kM * kNX; j += 256) r2s[j] = r2t[(size_t)ik * kM * kNX + j];
    for (int j = t; j < kM * kNY; j += 256) r3s[j] = r3t[(size_t)ik * kM * kNY + j];
    for (int j = t; j < kMR; j += 256)
        wrs[j] = make_float2(wr_re[ik * kMR + j], wr_im[ik * kMR + j]);
    __syncthreads();
    if (t < kNS) {
        float2 c0 = make_float2(0.f, 0.f), c1 = c0, c2 = c0, c3 = c0, c4 = c0, c5 = c0;
        float2 d0 = c0, d1 = c0, d2 = c0, d3 = c0, d4 = c0, d5 = c0;
        const float2* ap0 = alpha + (size_t)(b0 * kC + i) * kNF + t;
        const float2* ap1 = alpha + (size_t)(b1 * kC + i) * kNF + t;
        for (int m = 0; m < kNT; ++m) {
            float2 a0 = ap0[(size_t)m * kNS];
            float2 a1 = ap1[(size_t)m * kNS];
            float2 r;
            r = r1s[0 * kNT + m]; cfma(c0, a0, r); cfma(d0, a1, r);
            r = r1s[1 * kNT + m]; cfma(c1, a0, r); cfma(d1, a1, r);
            r = r1s[2 * kNT + m]; cfma(c2, a0, r); cfma(d2, a1, r);
            r = r1s[3 * kNT + m]; cfma(c3, a0, r); cfma(d3, a1, r);
            r = r1s[4 * kNT + m]; cfma(c4, a0, r); cfma(d4, a1, r);
            r = r1s[5 * kNT + m]; cfma(c5, a0, r); cfma(d5, a1, r);
        }
        T1a[0 * kNS + t] = c0; T1a[1 * kNS + t] = c1; T1a[2 * kNS + t] = c2;
        T1a[3 * kNS + t] = c3; T1a[4 * kNS + t] = c4; T1a[5 * kNS + t] = c5;
        T1b[0 * kNS + t] = d0; T1b[1 * kNS + t] = d1; T1b[2 * kNS + t] = d2;
        T1b[3 * kNS + t] = d3; T1b[4 * kNS + t] = d4; T1b[5 * kNS + t] = d5;
    }
    __syncthreads();
    for (int j = t; j < kM * kM * kNY; j += 256) {
        int l = j % kNY; int q = (j / kNY) % kM; int p = j / (kNY * kM);
        float2 a2 = make_float2(0.f, 0.f);
        float2 b2 = make_float2(0.f, 0.f);
        #pragma unroll
        for (int n = 0; n < kNX; ++n) {
            float2 r = r2s[q * kNX + n];
            cfma(a2, T1a[p * kNS + n * kNY + l], r);
            cfma(b2, T1b[p * kNS + n * kNY + l], r);
        }
        T2a[j] = a2;
        T2b[j] = b2;
    }
    __syncthreads();
    if (t < kMR) {
        int r = t % kM; int q = (t / kM) % kM; int p = t / (kM * kM);
        float2 t3a = make_float2(0.f, 0.f);
        float2 t3b = make_float2(0.f, 0.f);
        #pragma unroll
        for (int l = 0; l < kNY; ++l) {
            float2 rr = r3s[r * kNY + l];
            cfma(t3a, T2a[(p * kM + q) * kNY + l], rr);
            cfma(t3b, T2b[(p * kM + q) * kNY + l], rr);
        }
        float2 w = wrs[t];
        P[((size_t)(b0 * kC + k) * kC + i) * kMR + t] = cmul(w, t3a);
        P[((size_t)(b1 * kC + k) * kC + i) * kMR + t] = cmul(w, t3b);
    }
}

// ---------------------------------------------------------------------------
// K8a: V with fused or2 reduction. Block per (b,k,c) = 4096.
// o2row(b,c)[t] = -sum_i P[((b*16+c)*16+i)*216+t]  (redundant across k; L2-local)
// ---------------------------------------------------------------------------
__global__ __launch_bounds__(256) void k_x2v(
    const float2* __restrict__ P,
    const float2* __restrict__ e2t, const float2* __restrict__ e3t,
    float2* __restrict__ Vg)
{
    int bid = blockIdx.x;
    int c = bid & 15; int rest = bid >> 4;
    int k = rest & 15; int b = rest >> 4;
    int ck = c * kC + k;
    __shared__ float2 o2s[kMR];
    __shared__ float2 e2s[kM * kNX];
    __shared__ float2 e3s[kM * kNY];
    __shared__ float2 Us[kM * kM * kNY];
    int t = threadIdx.x;
    if (t < kMR) {
        float2 s = make_float2(0.f, 0.f);
        const float2* pp = P + (size_t)(b * kC + c) * kC * kMR + t;
        #pragma unroll
        for (int i = 0; i < kC; ++i) {
            float2 v = pp[(size_t)i * kMR];
            s.x += v.x; s.y += v.y;
        }
        o2s[t] = make_float2(-s.x, -s.y);
    }
    if (t < kM * kNX) e2s[t] = e2t[(size_t)ck * (kM * kNX) + t];
    if (t < kM * kNY) e3s[t] = e3t[(size_t)ck * (kM * kNY) + t];
    __syncthreads();
    for (int j = t; j < kM * kM * kNY; j += 256) {
        int y = j % kNY, pq = j / kNY;
        float2 u = make_float2(0.f, 0.f);
        #pragma unroll
        for (int m = 0; m < kM; ++m) cfma(u, o2s[pq * kM + m], e3s[m * kNY + y]);
        Us[j] = u;
    }
    __syncthreads();
    size_t vbase = ((size_t)(b * kC + k) * (kC * kM) + c * kM) * kVS;
    for (int j = t; j < kM * kVS; j += 256) {
        int p = j >> 8, s = j & 255;
        float2 v = make_float2(0.f, 0.f);
        if (s < kNS) {
            int x = s / kNY, y = s % kNY;
            #pragma unroll
            for (int q = 0; q < kM; ++q)
                cfma(v, Us[(p * kM + q) * kNY + y], e2s[q * kNX + x]);
        }
        Vg[vbase + (size_t)p * kVS + s] = v;
    }
}

// ---------------------------------------------------------------------------
// K8b: partial x2 GEMM, K split in 2 halves of 48. grid 1536.
// Writes float partials P2[kh][bk][z][s] (no scale).
// ---------------------------------------------------------------------------
__global__ __launch_bounds__(256) void k_x2gemm(
    const float2* __restrict__ Vg, const float2* __restrict__ e1t,
    float* __restrict__ P2)
{
    int bx = blockIdx.x;
    int bk = bx & 255;
    int zckh = bx >> 8;            // 0..5 = kh*3 + zc
    int kh = zckh / 3, zc = zckh % 3;
    int k = bk & 15;
    int z0 = zc * 13;
    __shared__ float2 e1w[48 * 16];      // rows kh*48..kh*48+47, zloc pad16
    __shared__ float2 Vs[2][4 * kVS];    // 2 x 8 KB chunk buffers (4 rows)
    int t = threadIdx.x;
    for (int j = t; j < 48 * 16; j += 256) {
        int row = j >> 4, zi = j & 15;
        int cp = kh * 48 + row;
        int c = cp / kM, p = cp % kM;
        float2 e = make_float2(0.f, 0.f);
        if (zi < 13)
            e = e1t[((size_t)(c * kC + k) * kM + p) * kNT + z0 + zi];
        e1w[j] = e;
    }

    int sl = t & 63, zt = t >> 6;
    const float2* vpan = Vg + (size_t)bk * (kC * kM) * kVS + (size_t)kh * 48 * kVS;
    #pragma unroll
    for (int j = 0; j < 4; ++j) Vs[0][j * 256 + t] = vpan[j * 256 + t];
    __syncthreads();

    float acc[4][4];
    #pragma unroll
    for (int zi = 0; zi < 4; ++zi)
        #pragma unroll
        for (int j = 0; j < 4; ++j) acc[zi][j] = 0.f;

    for (int ch = 0; ch < 12; ++ch) {
        int cur = ch & 1;
        if (ch + 1 < 12) {
            const float2* src = vpan + (size_t)(ch + 1) * 4 * kVS;
            #pragma unroll
            for (int j = 0; j < 4; ++j) Vs[cur ^ 1][j * 256 + t] = src[j * 256 + t];
        }
        #pragma unroll
        for (int r = 0; r < 4; ++r) {
            int row = ch * 4 + r;
            float2 vr[4];
            #pragma unroll
            for (int j = 0; j < 4; ++j) vr[j] = Vs[cur][r * 256 + sl + 64 * j];
            const int e1base = row * 16 + zt;
            #pragma unroll
            for (int zi = 0; zi < 4; ++zi) {
                float2 e = e1w[e1base + 4 * zi];
                #pragma unroll
                for (int j = 0; j < 4; ++j)
                    acc[zi][j] = fmaf(vr[j].x, e.x, fmaf(-vr[j].y, e.y, acc[zi][j]));
            }
        }
        __syncthreads();
    }

    size_t base = ((size_t)kh * kNIK + bk) * kNF;
    #pragma unroll
    for (int zi = 0; zi < 4; ++zi) {
        int zloc = zt + 4 * zi;
        if (zloc < 13) {
            size_t zb = base + (size_t)(z0 + zloc) * kNS;
            #pragma unroll
            for (int j = 0; j < 4; ++j) {
                int s = sl + 64 * j;
                if (s < kNS) P2[zb + s] = acc[zi][j];
            }
        }
    }
}

// ---------------------------------------------------------------------------
extern "C" void kernel_launch(void* const* d_in, const int* in_sizes, int n_in,
                              void* d_out, int out_size, void* d_ws, size_t ws_size,
                              hipStream_t stream) {
    (void)in_sizes; (void)n_in; (void)out_size; (void)ws_size;
    const float* x      = (const float*)d_in[0];
    const float* wp1_re = (const float*)d_in[1];
    const float* wp1_im = (const float*)d_in[2];
    const float* wp2_re = (const float*)d_in[3];
    const float* wp2_im = (const float*)d_in[4];
    const float* wp3_re = (const float*)d_in[5];
    const float* wp3_im = (const float*)d_in[6];
    const float* wr_re  = (const float*)d_in[7];
    const float* wr_im  = (const float*)d_in[8];
    float* out = (float*)d_out;

    const size_t big = (size_t)kNIK * kNF;  // 1,956,864 complex (15.7 MB)
    float2* A   = (float2*)d_ws;            // or1
    float2* Bb  = A + big;                  // alpha
    float2* Cc  = Bb + big;                 // H -> or2 partials -> x2 float partials
    float2* OR2 = Cc + big;                 // (unused; keeps table offsets stable)
    float2* r1t = OR2 + (size_t)kB * kC * kMR;
    float2* r2t = r1t + (size_t)kNIK * kM * kNT;
    float2* r3t = r2t + (size_t)kNIK * kM * kNX;
    float2* e1t = r3t + (size_t)kNIK * kM * kNY;
    float2* e2t = e1t + (size_t)kNIK * kM * kNT;
    float2* e3t = e2t + (size_t)kNIK * kM * kNX;
    float2* F39 = e3t + (size_t)kNIK * kM * kNY;
    float2* F14 = F39 + kNT * kNT;
    float2* Vg  = F14 + kNX * kNX;          // dedicated: 256*96*256 complex = 50 MB

    k_init<<<64, 256, 0, stream>>>(wp1_re, wp1_im, wp2_re, wp2_im, wp3_re, wp3_im,
                                   F39, F14, r1t, r2t, r3t, e1t, e2t, e3t);
    // fused forward DFT: x -> Bb (alpha)
    k_dft_fwd<<<dim3(kNIK, 3), 256, 0, stream>>>(x, F39, F14, Bb);
    // transfer function H -> Cc; or1 -> A
    k_H<<<kNIK, 256, 0, stream>>>(wr_re, wr_im, r1t, r2t, r3t, Cc);
    k_or1<<<kNF / kFCH, 256, 0, stream>>>(Bb, Cc, A);
    // or2 partials -> Cc (H dead)
    k_or2p<<<(kB / 2) * kC * kC, 256, 0, stream>>>(Bb, wr_re, wr_im, r1t, r2t, r3t, Cc);
    // x2: V (with fused or2-reduce) -> Vg; K-split GEMM partials -> Cc
    k_x2v<<<kB * kC * kC, 256, 0, stream>>>(Cc, e2t, e3t, Vg);
    k_x2gemm<<<kB * kC * 6, 256, 0, stream>>>(Vg, e1t, (float*)Cc);
    // fused inverse DFT of or1 (A) + x2 partial combine -> out (overwrite)
    k_idft_fused<<<dim3(kB * kC, 3), 256, 0, stream>>>(A, F39, F14, (const float*)Cc, out);
}